// Round 5
// baseline (223.067 us; speedup 1.0000x reference)
//
#include <hip/hip_runtime.h>
#include <math.h>

#define B_   2
#define S_   2048
#define DIM_ 1024
#define H_   16
#define HD_  64
#define BS_  (B_ * S_)              // 4096
#define BHSD ((size_t)B_ * H_ * S_ * HD_)   // 4M elements
#define CEXP 0.1803368801111244f    // log2(e) / sqrt(64)

typedef unsigned short u16;
typedef unsigned int   u32;
typedef short s16x8 __attribute__((ext_vector_type(8)));
typedef float f32x4 __attribute__((ext_vector_type(4)));

#define MFMA16(a, b, c) __builtin_amdgcn_mfma_f32_16x16x32_bf16((a), (b), (c), 0, 0, 0)

__device__ __forceinline__ u16 f2bf(float f) {
    u32 u = __float_as_uint(f);
    u += 0x7fffu + ((u >> 16) & 1u);            // RNE
    return (u16)(u >> 16);
}
__device__ __forceinline__ float bf2f(u16 h) {
    return __uint_as_float(((u32)h) << 16);
}
__device__ __forceinline__ u32 cvt_pk_bf16(float a, float b) {
    u32 r;
    asm("v_cvt_pk_bf16_f32 %0, %1, %2" : "=v"(r) : "v"(a), "v"(b));
    return r;
}
// async global->LDS, 16B/lane; LDS dest = wave-uniform base + lane*16
__device__ __forceinline__ void gl16(void* lds, const void* g) {
    __builtin_amdgcn_global_load_lds(
        (__attribute__((address_space(1))) void*)(g),
        (__attribute__((address_space(3))) void*)(lds), 16, 0, 0);
}

// ---------------------------------------------------------------------------
// x (fp32, 4096x1024) -> bf16
// ---------------------------------------------------------------------------
__global__ __launch_bounds__(256) void cvt_x(const float* __restrict__ X,
                                             u16* __restrict__ Y)
{
    const int i = blockIdx.x * 256 + threadIdx.x;
    const float4 a = *(const float4*)(X + (size_t)i * 8);
    const float4 b = *(const float4*)(X + (size_t)i * 8 + 4);
    s16x8 o;
    o[0] = (short)f2bf(a.x); o[1] = (short)f2bf(a.y);
    o[2] = (short)f2bf(a.z); o[3] = (short)f2bf(a.w);
    o[4] = (short)f2bf(b.x); o[5] = (short)f2bf(b.y);
    o[6] = (short)f2bf(b.z); o[7] = (short)f2bf(b.w);
    *(s16x8*)(Y + (size_t)i * 8) = o;
}

// ---------------------------------------------------------------------------
// W (fp32 [K][N]) -> Wt (bf16 [N][K]); z selects weight. 32x32 LDS transpose.
// ---------------------------------------------------------------------------
__global__ __launch_bounds__(256) void wtrans4(
    const float* __restrict__ W0, const float* __restrict__ W1,
    const float* __restrict__ W2, const float* __restrict__ W3,
    u16* __restrict__ T0, u16* __restrict__ T1,
    u16* __restrict__ T2, u16* __restrict__ T3)
{
    const float* W; u16* T;
    switch (blockIdx.z) {
        case 0: W = W0; T = T0; break;
        case 1: W = W1; T = T1; break;
        case 2: W = W2; T = T2; break;
        default: W = W3; T = T3; break;
    }
    __shared__ float tile[32][33];
    const int n0 = blockIdx.x * 32, k0 = blockIdx.y * 32;
    const int c = threadIdx.x & 31, rr = threadIdx.x >> 5;
#pragma unroll
    for (int i = 0; i < 4; ++i) {
        const int k = rr + i * 8;
        tile[k][c] = W[(size_t)(k0 + k) * DIM_ + n0 + c];
    }
    __syncthreads();
#pragma unroll
    for (int i = 0; i < 4; ++i) {
        const int n = rr + i * 8;
        T[(size_t)(n0 + n) * DIM_ + k0 + c] = f2bf(tile[c][n]);
    }
}

// ---------------------------------------------------------------------------
// concat biases: bias3[0:1024)=bq, [1024:2048)=bk, [2048:3072)=bv
// ---------------------------------------------------------------------------
__global__ __launch_bounds__(256) void cat_bias(
    const float* __restrict__ q, const float* __restrict__ k,
    const float* __restrict__ v, float* __restrict__ o)
{
    const int i = blockIdx.x * 256 + threadIdx.x;   // grid 12 -> 3072
    o[i] = (i < 1024) ? q[i] : ((i < 2048) ? k[i - 1024] : v[i - 2048]);
}

// ---------------------------------------------------------------------------
// bf16 MFMA GEMM, tile 128 x BN, BK=64, 256 threads (4 waves, 2x2 quadrants).
// A,Bt staged via global_load_lds (16B) into linear LDS, XOR-swizzled via
// pre-swizzled global source.
// EPI 0: bf16 head-major out into q|k|VT. VT = V transposed with kv-bit
//        permutation pi: bits [5,4,3,2] -> [2,5,4,3] within each 64-block
//        (makes the attention PV A-fragment lane-local).
// EPI 1: fp32 row-major out.
// ---------------------------------------------------------------------------
template<int BN, int HMIN, int EPI>
__global__ __launch_bounds__(256, 3) void gemm_mfma(
    const u16* __restrict__ A, const u16* __restrict__ Bt,
    const float* __restrict__ bias, void* __restrict__ Yv)
{
    __shared__ u16 As[128 * 64];
    __shared__ u16 Bs[BN * 64];

    const int tid = threadIdx.x, lane = tid & 63, wid = tid >> 6;
    const int l15 = lane & 15, lg = lane >> 4;
    const int row0 = blockIdx.x * 128, col0 = blockIdx.y * BN;
    const int wr = (wid >> 1) * 64;
    const int wc = (wid & 1) * (BN / 2);
    constexpr int NM = 4, NN = BN / 32, BCH = BN / 32;

    const int l8 = lane >> 3, l7 = lane & 7;
    const int colE = ((l7 ^ l8) << 3);          // k-element offset (swizzled)

    const u16* aptr[4]; u16* aldp[4];
#pragma unroll
    for (int i = 0; i < 4; ++i) {
        const int ci = wid * 4 + i;
        const int rr = row0 + ci * 8 + l8;
        size_t a0;
        if (HMIN)
            a0 = (((size_t)(rr >> 11) * H_) * S_ + (rr & (S_ - 1))) * HD_ + colE;
        else
            a0 = (size_t)rr * DIM_ + colE;
        aptr[i] = A + a0;
        aldp[i] = As + ci * 512;
    }
    const u16* bptr[BCH]; u16* bldp[BCH];
#pragma unroll
    for (int i = 0; i < BCH; ++i) {
        const int ci = wid * BCH + i;
        const int rr = col0 + ci * 8 + l8;
        bptr[i] = Bt + (size_t)rr * DIM_ + colE;
        bldp[i] = Bs + ci * 512;
    }
    const size_t astep = HMIN ? (size_t)S_ * HD_ : 64;

    f32x4 acc[NM][NN];
#pragma unroll
    for (int m = 0; m < NM; ++m)
#pragma unroll
        for (int n = 0; n < NN; ++n) acc[m][n] = (f32x4){0.f, 0.f, 0.f, 0.f};

    for (int k0 = 0; k0 < DIM_; k0 += 64) {
        __syncthreads();   // previous frag reads done
#pragma unroll
        for (int i = 0; i < 4; ++i) gl16(aldp[i], aptr[i]);
#pragma unroll
        for (int i = 0; i < BCH; ++i) gl16(bldp[i], bptr[i]);
#pragma unroll
        for (int i = 0; i < 4; ++i) aptr[i] += astep;
#pragma unroll
        for (int i = 0; i < BCH; ++i) bptr[i] += 64;
        __syncthreads();   // loads drained

        s16x8 af[NM][2], bfr[NN][2];
#pragma unroll
        for (int m = 0; m < NM; ++m) {
            const int row = wr + m * 16 + l15;
#pragma unroll
            for (int kf = 0; kf < 2; ++kf)
                af[m][kf] = *(const s16x8*)&As[row * 64 +
                    (((kf * 64 + lg * 16) ^ ((l15 & 7) << 4)) >> 1)];
        }
#pragma unroll
        for (int n = 0; n < NN; ++n) {
            const int row = wc + n * 16 + l15;
#pragma unroll
            for (int kf = 0; kf < 2; ++kf)
                bfr[n][kf] = *(const s16x8*)&Bs[row * 64 +
                    (((kf * 64 + lg * 16) ^ ((l15 & 7) << 4)) >> 1)];
        }
        __builtin_amdgcn_s_setprio(1);
#pragma unroll
        for (int m = 0; m < NM; ++m)
#pragma unroll
            for (int n = 0; n < NN; ++n) {
                acc[m][n] = MFMA16(af[m][0], bfr[n][0], acc[m][n]);
                acc[m][n] = MFMA16(af[m][1], bfr[n][1], acc[m][n]);
            }
        __builtin_amdgcn_s_setprio(0);
    }

    // epilogue
#pragma unroll
    for (int n = 0; n < NN; ++n) {
        const int cc = col0 + wc + n * 16 + l15;
        const float bv = bias[cc];
#pragma unroll
        for (int m = 0; m < NM; ++m)
#pragma unroll
            for (int r = 0; r < 4; ++r) {
                const int rr = row0 + wr + m * 16 + lg * 4 + r;
                const float val = acc[m][n][r] + bv;
                if (EPI == 0) {
                    u16* Y = (u16*)Yv;
                    const int which = cc >> 10, hh = (cc >> 6) & (H_ - 1), d = cc & 63;
                    const int b = rr >> 11, s = rr & (S_ - 1);
                    size_t dst;
                    if (which == 2) {
                        // V^T with kv permutation pi within each 64-block:
                        // bits {2,3}->{3,4}, {4}->{5}, {5}->{2}
                        const int sp = (s & ~60) | ((s & 12) << 1)
                                     | ((s & 16) << 1) | ((s & 32) >> 3);
                        dst = 2 * BHSD + ((size_t)(b * H_ + hh) * HD_ + d) * S_ + sp;
                    } else {
                        dst = (size_t)which * BHSD
                            + (((size_t)b * H_ + hh) * S_ + s) * HD_ + d;
                    }
                    Y[dst] = f2bf(val);
                } else {
                    ((float*)Yv)[(size_t)rr * DIM_ + cc] = val;
                }
            }
    }
}

// ---------------------------------------------------------------------------
// RoPE in place on bf16 [B*H][S][64]; z=0: q (pre-scaled by log2(e)/8), z=1: k.
// ---------------------------------------------------------------------------
__global__ __launch_bounds__(256) void rope2(u16* __restrict__ Tq, u16* __restrict__ Tk,
                                             const float* __restrict__ theta)
{
    u16* T = blockIdx.z ? Tk : Tq;
    const float scl = blockIdx.z ? 1.0f : CEXP;
    const int row = blockIdx.x * 8 + (threadIdx.x >> 5);
    const int j   = threadIdx.x & 31;
    const int s   = row & (S_ - 1);
    u16* rp = T + (size_t)row * HD_;
    const u32 pr = *(const u32*)(rp + 2 * j);
    const float x1 = bf2f((u16)(pr & 0xffffu));
    const float x2 = bf2f((u16)(pr >> 16));
    float sn, cs;
    sincosf((float)s * theta[j], &sn, &cs);
    const u16 o1 = f2bf((x1 * cs - x2 * sn) * scl);
    const u16 o2 = f2bf((x1 * sn + x2 * cs) * scl);
    rp[j]      = o1;    // wave-internal: loads complete before stores
    rp[32 + j] = o2;
}

// ---------------------------------------------------------------------------
// Causal flash attention: one wave per 16-row q-tile. No LDS, no barriers.
// Grid (32 bh, 32 i); block 256 = 4 independent waves, wave w -> qt = i*4+w
// (i reversed so heavy blocks dispatch first; same-block waves share KV
// stream for L1 reuse; bh-fast grid pins each head's K/V to one XCD's L2).
// Q pre-scaled by log2(e)/8; scores used directly as exp2 args.
// K: [bh][s][64]. VT: [bh][64][s] with kv-bit-perm pi baked in -> PV
// A-fragment is lane-local (8 cvt_pk, no shuffles). Output in place into Q.
// ---------------------------------------------------------------------------
__global__ __launch_bounds__(256, 4) void attn16(
    u16* __restrict__ Q, const u16* __restrict__ K, const u16* __restrict__ VT)
{
    const int bh = blockIdx.x;
    const int i  = 31 - blockIdx.y;
    const int wid = threadIdx.x >> 6, lane = threadIdx.x & 63;
    const int l15 = lane & 15, lg = lane >> 4;
    const int qt = i * 4 + wid;          // 0..127
    const int q0 = qt * 16;
    const int nt = (qt >> 2) + 1;
    const int dsub = qt & 3;             // diagonal sub-tile in last kv-tile

    u16* Qg = Q + (size_t)bh * S_ * HD_;
    const u16* Kg = K + (size_t)bh * S_ * HD_;
    const u16* Vg = VT + (size_t)bh * HD_ * S_;

    // Q B-fragments: Q[q0+l15][half*32 + lg*8 + j]
    s16x8 qf[2];
    {
        const u16* qrow = Qg + (size_t)(q0 + l15) * HD_ + lg * 8;
        qf[0] = *(const s16x8*)(qrow);
        qf[1] = *(const s16x8*)(qrow + 32);
    }

    // K pointers: row sub*16+l15, k-slice lg*8 (advance 64 rows per tile)
    const u16* kp[4];
#pragma unroll
    for (int sub = 0; sub < 4; ++sub)
        kp[sub] = Kg + (size_t)(sub * 16 + l15) * HD_ + lg * 8;
    // V pointers: row d = n*16+l15, col lg*8 (advance 64 cols per tile)
    const u16* vp[4];
#pragma unroll
    for (int n = 0; n < 4; ++n)
        vp[n] = Vg + (size_t)(n * 16 + l15) * S_ + lg * 8;

    f32x4 o[4];
#pragma unroll
    for (int n = 0; n < 4; ++n) o[n] = (f32x4){0.f, 0.f, 0.f, 0.f};
    float mI = -1e30f, lI = 0.f;

    for (int t = 0; t < nt; ++t) {
        // ---- swapped QK^T: s[sub][r] = S[kv=t*64+sub*16+lg*4+r][q=q0+l15]
        f32x4 sc[4];
#pragma unroll
        for (int sub = 0; sub < 4; ++sub) {
            const s16x8 kf0 = *(const s16x8*)(kp[sub]);
            const s16x8 kf1 = *(const s16x8*)(kp[sub] + 32);
            kp[sub] += 64 * HD_;
            f32x4 z = (f32x4){0.f, 0.f, 0.f, 0.f};
            z = MFMA16(kf0, qf[0], z);
            sc[sub] = MFMA16(kf1, qf[1], z);
        }

        if (t == nt - 1) {   // diagonal tile: aligned 16x16 sub-blocks
#pragma unroll
            for (int sub = 0; sub < 4; ++sub) {
                if (sub == dsub) {
#pragma unroll
                    for (int r = 0; r < 4; ++r)
                        if (lg * 4 + r > l15) sc[sub][r] = -1e30f;
                } else if (sub > dsub) {
#pragma unroll
                    for (int r = 0; r < 4; ++r) sc[sub][r] = -1e30f;
                }
            }
        }

        // ---- online softmax (q = l15; combine lg groups via shfl)
        float pm = -1e30f;
#pragma unroll
        for (int sub = 0; sub < 4; ++sub)
#pragma unroll
            for (int r = 0; r < 4; ++r) pm = fmaxf(pm, sc[sub][r]);
        pm = fmaxf(pm, __shfl_xor(pm, 16));
        pm = fmaxf(pm, __shfl_xor(pm, 32));
        if (!__all(pm - mI <= 8.f)) {    // defer-max (log2 units)
            const float mn = fmaxf(mI, pm);
            const float al = __builtin_amdgcn_exp2f(mI - mn);
            mI = mn; lI *= al;
#pragma unroll
            for (int r = 0; r < 4; ++r) {
                const float at = __shfl(al, lg * 4 + r);
#pragma unroll
                for (int n = 0; n < 4; ++n) o[n][r] *= at;
            }
        }
        float p[4][4];
        float ps = 0.f;
#pragma unroll
        for (int sub = 0; sub < 4; ++sub)
#pragma unroll
            for (int r = 0; r < 4; ++r) {
                p[sub][r] = __builtin_amdgcn_exp2f(sc[sub][r] - mI);
                ps += p[sub][r];
            }
        ps += __shfl_xor(ps, 16);
        ps += __shfl_xor(ps, 32);
        lI += ps;

        // ---- PV: A-frag lane-local via pi-permuted VT
        union { s16x8 v; u32 w[4]; } af[2];
#pragma unroll
        for (int step = 0; step < 2; ++step)
#pragma unroll
            for (int jj = 0; jj < 4; ++jj) {
                const int sub = (jj >> 1) * 2 + step;
                const int r0  = (jj & 1) * 2;
                af[step].w[jj] = cvt_pk_bf16(p[sub][r0], p[sub][r0 + 1]);
            }
#pragma unroll
        for (int n = 0; n < 4; ++n) {
            const s16x8 vf0 = *(const s16x8*)(vp[n]);
            const s16x8 vf1 = *(const s16x8*)(vp[n] + 32);
            vp[n] += 64;
            o[n] = MFMA16(af[0].v, vf0, o[n]);
            o[n] = MFMA16(af[1].v, vf1, o[n]);
        }
    }

    // ---- epilogue: O / l, write bf16 in place into Q (own 16 rows only)
    const float il = 1.f / lI;
    u16* orow = Qg + (size_t)(q0 + lg * 4) * HD_ + l15;
#pragma unroll
    for (int r = 0; r < 4; ++r) {
        const float ilr = __shfl(il, lg * 4 + r);
#pragma unroll
        for (int n = 0; n < 4; ++n)
            orow[r * HD_ + n * 16] = f2bf(o[n][r] * ilr);
    }
}

// ---------------------------------------------------------------------------
extern "C" void kernel_launch(void* const* d_in, const int* in_sizes, int n_in,
                              void* d_out, int out_size, void* d_ws, size_t ws_size,
                              hipStream_t stream)
{
    (void)in_sizes; (void)n_in; (void)out_size; (void)ws_size;
    const float* x     = (const float*)d_in[0];
    const float* theta = (const float*)d_in[2];
    const float* Wq    = (const float*)d_in[3];
    const float* bq    = (const float*)d_in[4];
    const float* Wk    = (const float*)d_in[5];
    const float* bk    = (const float*)d_in[6];
    const float* Wv    = (const float*)d_in[7];
    const float* bv    = (const float*)d_in[8];
    const float* Wo    = (const float*)d_in[9];
    const float* bo    = (const float*)d_in[10];
    float* out = (float*)d_out;

    // ws (u16): xb 4M | wtq|wtk|wtv 3M | wto 1M | q 4M | k 4M | VT 4M | bias3
    u16* xb  = (u16*)d_ws;
    u16* wtq = xb + (size_t)BS_ * DIM_;
    u16* wtk = wtq + (size_t)DIM_ * DIM_;
    u16* wtv = wtk + (size_t)DIM_ * DIM_;
    u16* wto = wtv + (size_t)DIM_ * DIM_;
    u16* qws = wto + (size_t)DIM_ * DIM_;
    u16* kws = qws + BHSD;
    u16* vtw = kws + BHSD;
    float* bias3 = (float*)(vtw + BHSD);

    const dim3 blk(256);

    cvt_x<<<dim3(BS_ * DIM_ / 8 / 256), blk, 0, stream>>>(x, xb);
    wtrans4<<<dim3(32, 32, 4), blk, 0, stream>>>(Wq, Wk, Wv, Wo, wtq, wtk, wtv, wto);
    cat_bias<<<dim3(12), blk, 0, stream>>>(bq, bk, bv, bias3);

    // fused QKV projection: q,k head-major; V written transposed+pi-permuted
    gemm_mfma<128, 0, 0><<<dim3(32, 24), blk, 0, stream>>>(xb, wtq, bias3, qws);

    rope2<<<dim3(B_ * H_ * S_ / 8, 1, 2), blk, 0, stream>>>(qws, kws, theta);

    attn16<<<dim3(32, 32), blk, 0, stream>>>(qws, kws, vtw);

    // output projection (head-major A in, fp32 row-major out)
    gemm_mfma<64, 1, 1><<<dim3(32, 16), blk, 0, stream>>>(qws, wto, bo, out);
}

// Round 6
// 127.719 us; speedup vs baseline: 1.7465x; 1.7465x over previous
//
#include <hip/hip_runtime.h>
#include <math.h>

#define B_   2
#define S_   2048
#define DIM_ 1024
#define H_   16
#define HD_  64
#define BS_  (B_ * S_)              // 4096
#define BHSD ((size_t)B_ * H_ * S_ * HD_)   // 4M elements
#define CEXP 0.1803368801111244f    // log2(e) / sqrt(64)

typedef unsigned short u16;
typedef unsigned int   u32;
typedef short s16x8 __attribute__((ext_vector_type(8)));
typedef float f32x4 __attribute__((ext_vector_type(4)));
typedef float f32x16 __attribute__((ext_vector_type(16)));

#define MFMA16(a, b, c) __builtin_amdgcn_mfma_f32_16x16x32_bf16((a), (b), (c), 0, 0, 0)
#define MFMA32(a, b, c) __builtin_amdgcn_mfma_f32_32x32x16_bf16((a), (b), (c), 0, 0, 0)

__device__ __forceinline__ u16 f2bf(float f) {
    u32 u = __float_as_uint(f);
    u += 0x7fffu + ((u >> 16) & 1u);            // RNE
    return (u16)(u >> 16);
}
__device__ __forceinline__ float bf2f(u16 h) {
    return __uint_as_float(((u32)h) << 16);
}
__device__ __forceinline__ u32 cvt_pk_bf16(float a, float b) {
    u32 r;
    asm("v_cvt_pk_bf16_f32 %0, %1, %2" : "=v"(r) : "v"(a), "v"(b));
    return r;
}
// async global->LDS, 16B/lane; LDS dest = wave-uniform base + lane*16
__device__ __forceinline__ void gl16(void* lds, const void* g) {
    __builtin_amdgcn_global_load_lds(
        (__attribute__((address_space(1))) void*)(g),
        (__attribute__((address_space(3))) void*)(lds), 16, 0, 0);
}

// ---------------------------------------------------------------------------
// x (fp32, 4096x1024) -> bf16
// ---------------------------------------------------------------------------
__global__ __launch_bounds__(256) void cvt_x(const float* __restrict__ X,
                                             u16* __restrict__ Y)
{
    const int i = blockIdx.x * 256 + threadIdx.x;
    const float4 a = *(const float4*)(X + (size_t)i * 8);
    const float4 b = *(const float4*)(X + (size_t)i * 8 + 4);
    s16x8 o;
    o[0] = (short)f2bf(a.x); o[1] = (short)f2bf(a.y);
    o[2] = (short)f2bf(a.z); o[3] = (short)f2bf(a.w);
    o[4] = (short)f2bf(b.x); o[5] = (short)f2bf(b.y);
    o[6] = (short)f2bf(b.z); o[7] = (short)f2bf(b.w);
    *(s16x8*)(Y + (size_t)i * 8) = o;
}

// ---------------------------------------------------------------------------
// W (fp32 [K][N]) -> Wt (bf16 [N][K]); z selects weight. 32x32 LDS transpose.
// ---------------------------------------------------------------------------
__global__ __launch_bounds__(256) void wtrans4(
    const float* __restrict__ W0, const float* __restrict__ W1,
    const float* __restrict__ W2, const float* __restrict__ W3,
    u16* __restrict__ T0, u16* __restrict__ T1,
    u16* __restrict__ T2, u16* __restrict__ T3)
{
    const float* W; u16* T;
    switch (blockIdx.z) {
        case 0: W = W0; T = T0; break;
        case 1: W = W1; T = T1; break;
        case 2: W = W2; T = T2; break;
        default: W = W3; T = T3; break;
    }
    __shared__ float tile[32][33];
    const int n0 = blockIdx.x * 32, k0 = blockIdx.y * 32;
    const int c = threadIdx.x & 31, rr = threadIdx.x >> 5;
#pragma unroll
    for (int i = 0; i < 4; ++i) {
        const int k = rr + i * 8;
        tile[k][c] = W[(size_t)(k0 + k) * DIM_ + n0 + c];
    }
    __syncthreads();
#pragma unroll
    for (int i = 0; i < 4; ++i) {
        const int n = rr + i * 8;
        T[(size_t)(n0 + n) * DIM_ + k0 + c] = f2bf(tile[c][n]);
    }
}

// ---------------------------------------------------------------------------
// concat biases: bias3[0:1024)=bq, [1024:2048)=bk, [2048:3072)=bv
// ---------------------------------------------------------------------------
__global__ __launch_bounds__(256) void cat_bias(
    const float* __restrict__ q, const float* __restrict__ k,
    const float* __restrict__ v, float* __restrict__ o)
{
    const int i = blockIdx.x * 256 + threadIdx.x;   // grid 12 -> 3072
    o[i] = (i < 1024) ? q[i] : ((i < 2048) ? k[i - 1024] : v[i - 2048]);
}

// ---------------------------------------------------------------------------
// bf16 MFMA GEMM, tile 128 x BN, BK=64, 256 threads (4 waves, 2x2 quadrants).
// A,Bt staged via global_load_lds (16B) into linear LDS, XOR-swizzled via
// pre-swizzled global source.
// EPI 0: bf16 head-major out into q|k|VT (VT = V transposed + s-bit2<->3 swap).
// EPI 1: fp32 row-major out.
// ---------------------------------------------------------------------------
template<int BN, int HMIN, int EPI>
__global__ __launch_bounds__(256, 3) void gemm_mfma(
    const u16* __restrict__ A, const u16* __restrict__ Bt,
    const float* __restrict__ bias, void* __restrict__ Yv)
{
    __shared__ u16 As[128 * 64];
    __shared__ u16 Bs[BN * 64];

    const int tid = threadIdx.x, lane = tid & 63, wid = tid >> 6;
    const int l15 = lane & 15, lg = lane >> 4;
    const int row0 = blockIdx.x * 128, col0 = blockIdx.y * BN;
    const int wr = (wid >> 1) * 64;
    const int wc = (wid & 1) * (BN / 2);
    constexpr int NM = 4, NN = BN / 32, BCH = BN / 32;

    const int l8 = lane >> 3, l7 = lane & 7;
    const int colE = ((l7 ^ l8) << 3);          // k-element offset (swizzled)

    const u16* aptr[4]; u16* aldp[4];
#pragma unroll
    for (int i = 0; i < 4; ++i) {
        const int ci = wid * 4 + i;
        const int rr = row0 + ci * 8 + l8;
        size_t a0;
        if (HMIN)
            a0 = (((size_t)(rr >> 11) * H_) * S_ + (rr & (S_ - 1))) * HD_ + colE;
        else
            a0 = (size_t)rr * DIM_ + colE;
        aptr[i] = A + a0;
        aldp[i] = As + ci * 512;
    }
    const u16* bptr[BCH]; u16* bldp[BCH];
#pragma unroll
    for (int i = 0; i < BCH; ++i) {
        const int ci = wid * BCH + i;
        const int rr = col0 + ci * 8 + l8;
        bptr[i] = Bt + (size_t)rr * DIM_ + colE;
        bldp[i] = Bs + ci * 512;
    }
    const size_t astep = HMIN ? (size_t)S_ * HD_ : 64;

    f32x4 acc[NM][NN];
#pragma unroll
    for (int m = 0; m < NM; ++m)
#pragma unroll
        for (int n = 0; n < NN; ++n) acc[m][n] = (f32x4){0.f, 0.f, 0.f, 0.f};

    for (int k0 = 0; k0 < DIM_; k0 += 64) {
        __syncthreads();   // previous frag reads done
#pragma unroll
        for (int i = 0; i < 4; ++i) gl16(aldp[i], aptr[i]);
#pragma unroll
        for (int i = 0; i < BCH; ++i) gl16(bldp[i], bptr[i]);
#pragma unroll
        for (int i = 0; i < 4; ++i) aptr[i] += astep;
#pragma unroll
        for (int i = 0; i < BCH; ++i) bptr[i] += 64;
        __syncthreads();   // loads drained

        s16x8 af[NM][2], bfr[NN][2];
#pragma unroll
        for (int m = 0; m < NM; ++m) {
            const int row = wr + m * 16 + l15;
#pragma unroll
            for (int kf = 0; kf < 2; ++kf)
                af[m][kf] = *(const s16x8*)&As[row * 64 +
                    (((kf * 64 + lg * 16) ^ ((l15 & 7) << 4)) >> 1)];
        }
#pragma unroll
        for (int n = 0; n < NN; ++n) {
            const int row = wc + n * 16 + l15;
#pragma unroll
            for (int kf = 0; kf < 2; ++kf)
                bfr[n][kf] = *(const s16x8*)&Bs[row * 64 +
                    (((kf * 64 + lg * 16) ^ ((l15 & 7) << 4)) >> 1)];
        }
        __builtin_amdgcn_s_setprio(1);
#pragma unroll
        for (int m = 0; m < NM; ++m)
#pragma unroll
            for (int n = 0; n < NN; ++n) {
                acc[m][n] = MFMA16(af[m][0], bfr[n][0], acc[m][n]);
                acc[m][n] = MFMA16(af[m][1], bfr[n][1], acc[m][n]);
            }
        __builtin_amdgcn_s_setprio(0);
    }

    // epilogue
#pragma unroll
    for (int n = 0; n < NN; ++n) {
        const int cc = col0 + wc + n * 16 + l15;
        const float bv = bias[cc];
#pragma unroll
        for (int m = 0; m < NM; ++m)
#pragma unroll
            for (int r = 0; r < 4; ++r) {
                const int rr = row0 + wr + m * 16 + lg * 4 + r;
                const float val = acc[m][n][r] + bv;
                if (EPI == 0) {
                    u16* Y = (u16*)Yv;
                    const int which = cc >> 10, hh = (cc >> 6) & (H_ - 1), d = cc & 63;
                    const int b = rr >> 11, s = rr & (S_ - 1);
                    size_t dst;
                    if (which == 2) {
                        // V^T, with s bits 2<->3 swapped (PV contraction perm)
                        const int sp = (s & ~12) | ((s & 4) << 1) | ((s & 8) >> 1);
                        dst = 2 * BHSD + ((size_t)(b * H_ + hh) * HD_ + d) * S_ + sp;
                    } else {
                        dst = (size_t)which * BHSD
                            + (((size_t)b * H_ + hh) * S_ + s) * HD_ + d;
                    }
                    Y[dst] = f2bf(val);
                } else {
                    ((float*)Yv)[(size_t)rr * DIM_ + cc] = val;
                }
            }
    }
}

// ---------------------------------------------------------------------------
// RoPE in place on bf16 [B*H][S][64]; z=0: q (pre-scaled by log2(e)/8), z=1: k.
// ---------------------------------------------------------------------------
__global__ __launch_bounds__(256) void rope2(u16* __restrict__ Tq, u16* __restrict__ Tk,
                                             const float* __restrict__ theta)
{
    u16* T = blockIdx.z ? Tk : Tq;
    const float scl = blockIdx.z ? 1.0f : CEXP;
    const int row = blockIdx.x * 8 + (threadIdx.x >> 5);
    const int j   = threadIdx.x & 31;
    const int s   = row & (S_ - 1);
    u16* rp = T + (size_t)row * HD_;
    const u32 pr = *(const u32*)(rp + 2 * j);
    const float x1 = bf2f((u16)(pr & 0xffffu));
    const float x2 = bf2f((u16)(pr >> 16));
    float sn, cs;
    sincosf((float)s * theta[j], &sn, &cs);
    const u16 o1 = f2bf((x1 * cs - x2 * sn) * scl);
    const u16 o2 = f2bf((x1 * sn + x2 * cs) * scl);
    rp[j]      = o1;    // wave-internal: loads complete before stores
    rp[32 + j] = o2;
}

// ---------------------------------------------------------------------------
// bf16 MFMA causal flash attention, 32x32x16, swapped QK^T, KVBLK=64,
// double-buffered K/V LDS staging, in-register log2-domain softmax.
// Grid (32 bh FAST, 16 qb reversed): XCD = bh%8 -> per-XCD KV = 4 heads =
// 2 MB, L2-resident. 256 threads = 4 waves; wave w owns q rows
// qb*128 + w*32 .. +31. Q pre-scaled by log2(e)/8. Output in place into Q.
// ---------------------------------------------------------------------------
__global__ __launch_bounds__(256, 3) void attn_mfma(
    u16* __restrict__ Q, const u16* __restrict__ K, const u16* __restrict__ VT)
{
    const int bh = blockIdx.x;
    const int qb = 15 - blockIdx.y;        // heavy blocks dispatch first
    const int q0 = qb * 128;
    const int nt = 2 * qb + 2;

    u16* Qg = Q + (size_t)bh * S_ * HD_;
    const u16* Kg = K + (size_t)bh * S_ * HD_;
    const u16* Vg = VT + (size_t)bh * HD_ * S_;   // permuted [64][2048]

    __shared__ u16 KsA[2][64 * 64];   // 2 x 8 KB
    __shared__ u16 VsA[2][64 * 64];   // 2 x 8 KB

    const int tid = threadIdx.x, wid = tid >> 6, lane = tid & 63;
    const int l31 = lane & 31, h = lane >> 5;
    const int swz = l31 & 7;
    const int qw0 = q0 + wid * 32;

    // Q B-fragments: rows qw0 + l31, k = ks*16 + h*8 (pre-scaled by CEXP)
    s16x8 qf[4];
    {
        const u16* qrow = Qg + (size_t)(qw0 + l31) * HD_ + h * 8;
#pragma unroll
        for (int ks = 0; ks < 4; ++ks)
            qf[ks] = *(const s16x8*)(qrow + ks * 16);
    }

    f32x16 o0, o1;
#pragma unroll
    for (int r = 0; r < 16; ++r) { o0[r] = 0.f; o1[r] = 0.f; }
    float mI = -1e30f, lI = 0.f;

    // staging: per wave 2 K-chunk-groups + 2 V-chunk-groups
    const int srow = (lane >> 3);          // 0..7 within group
    const int sslt = (lane & 7);
#pragma unroll
    for (int i = 0; i < 2; ++i) {          // prologue: tile 0 -> buf 0
        const int grp = wid * 2 + i;
        const int row = grp * 8 + srow;
        const int ss  = (sslt ^ (row & 7)) << 3;
        gl16(&KsA[0][grp * 512], Kg + (size_t)row * HD_ + ss);
        gl16(&VsA[0][grp * 512], Vg + (size_t)row * S_ + ss);
    }
    __syncthreads();

    int buf = 0;
    for (int t = 0; t < nt; ++t) {
        const int j0 = t * 64;
        if (t + 1 < nt) {                  // prefetch next tile
            const int j1 = j0 + 64;
#pragma unroll
            for (int i = 0; i < 2; ++i) {
                const int grp = wid * 2 + i;
                const int row = grp * 8 + srow;
                const int ss  = (sslt ^ (row & 7)) << 3;
                gl16(&KsA[buf ^ 1][grp * 512], Kg + (size_t)(j1 + row) * HD_ + ss);
                gl16(&VsA[buf ^ 1][grp * 512], Vg + (size_t)row * S_ + j1 + ss);
            }
        }

        if (j0 <= qw0 + 31) {              // wave-uniform skip of masked tiles
            const u16* Kb = KsA[buf];
            const u16* Vb = VsA[buf];

            // ---- swapped QK^T: sc[sub][reg] = S[kv=j0+sub*32+crow(reg,h)][q=qw0+l31]
            f32x16 s0, s1;
#pragma unroll
            for (int r = 0; r < 16; ++r) { s0[r] = 0.f; s1[r] = 0.f; }
            __builtin_amdgcn_s_setprio(1);
#pragma unroll
            for (int ks = 0; ks < 4; ++ks) {
                const int sl = (((ks << 1) | h) ^ swz) << 3;
                const s16x8 k0 = *(const s16x8*)&Kb[l31 * 64 + sl];
                const s16x8 k1 = *(const s16x8*)&Kb[(32 + l31) * 64 + sl];
                s0 = MFMA32(k0, qf[ks], s0);
                s1 = MFMA32(k1, qf[ks], s1);
            }
            __builtin_amdgcn_s_setprio(0);

            if (j0 + 63 > qw0) {           // diagonal region: causal mask
                const int qg = qw0 + l31;
#pragma unroll
                for (int r = 0; r < 16; ++r) {
                    const int kvr = j0 + (r & 3) + ((r >> 2) << 3) + (h << 2);
                    if (kvr > qg)      s0[r] = -1e30f;
                    if (kvr + 32 > qg) s1[r] = -1e30f;
                }
            }

            // ---- online softmax, log2 domain, defer-max (THR = 8)
            float pm = -1e30f;
#pragma unroll
            for (int r = 0; r < 16; ++r) pm = fmaxf(pm, fmaxf(s0[r], s1[r]));
            pm = fmaxf(pm, __shfl_xor(pm, 32));
            if (!__all(pm - mI <= 8.f)) {
                const float mn = fmaxf(mI, pm);
                const float al = __builtin_amdgcn_exp2f(mI - mn);
                mI = mn; lI *= al;
#pragma unroll
                for (int r = 0; r < 16; ++r) {
                    const float at = __shfl(al, (r & 3) + ((r >> 2) << 3) + (h << 2));
                    o0[r] *= at; o1[r] *= at;
                }
            }
            float p0[16], p1[16];
            float ps = 0.f;
#pragma unroll
            for (int r = 0; r < 16; ++r) {
                p0[r] = __builtin_amdgcn_exp2f(s0[r] - mI); ps += p0[r];
            }
#pragma unroll
            for (int r = 0; r < 16; ++r) {
                p1[r] = __builtin_amdgcn_exp2f(s1[r] - mI); ps += p1[r];
            }
            ps += __shfl_xor(ps, 32);
            lI += ps;

            // ---- PV: lane-local P fragments (contraction-permuted V^T)
            __builtin_amdgcn_s_setprio(1);
#pragma unroll
            for (int sub = 0; sub < 2; ++sub) {
#pragma unroll
                for (int j = 0; j < 2; ++j) {
                    union { s16x8 v; u32 w[4]; } pa;
#pragma unroll
                    for (int q2 = 0; q2 < 4; ++q2) {
                        const float a = sub ? p1[j * 8 + q2 * 2]     : p0[j * 8 + q2 * 2];
                        const float b = sub ? p1[j * 8 + q2 * 2 + 1] : p0[j * 8 + q2 * 2 + 1];
                        pa.w[q2] = cvt_pk_bf16(a, b);
                    }
                    const int sl = (((sub << 2) | (j << 1) | h) ^ swz) << 3;
                    const s16x8 v0 = *(const s16x8*)&Vb[l31 * 64 + sl];
                    const s16x8 v1 = *(const s16x8*)&Vb[(32 + l31) * 64 + sl];
                    o0 = MFMA32(pa.v, v0, o0);
                    o1 = MFMA32(pa.v, v1, o1);
                }
            }
            __builtin_amdgcn_s_setprio(0);
        }

        __syncthreads();                   // drains prefetch; buf handoff
        buf ^= 1;
    }

    // ---- epilogue: O / l, write bf16 in place into Q
    const float il = 1.f / lI;
#pragma unroll
    for (int r = 0; r < 16; ++r) {
        const int cr = (r & 3) + ((r >> 2) << 3) + (h << 2);
        const float ilr = __shfl(il, cr);
        u16* orow = Qg + (size_t)(qw0 + cr) * HD_;
        orow[l31]      = f2bf(o0[r] * ilr);
        orow[32 + l31] = f2bf(o1[r] * ilr);
    }
}

// ---------------------------------------------------------------------------
extern "C" void kernel_launch(void* const* d_in, const int* in_sizes, int n_in,
                              void* d_out, int out_size, void* d_ws, size_t ws_size,
                              hipStream_t stream)
{
    (void)in_sizes; (void)n_in; (void)out_size; (void)ws_size;
    const float* x     = (const float*)d_in[0];
    const float* theta = (const float*)d_in[2];
    const float* Wq    = (const float*)d_in[3];
    const float* bq    = (const float*)d_in[4];
    const float* Wk    = (const float*)d_in[5];
    const float* bk    = (const float*)d_in[6];
    const float* Wv    = (const float*)d_in[7];
    const float* bv    = (const float*)d_in[8];
    const float* Wo    = (const float*)d_in[9];
    const float* bo    = (const float*)d_in[10];
    float* out = (float*)d_out;

    // ws (u16): xb 4M | wtq|wtk|wtv 3M | wto 1M | q 4M | k 4M | VT 4M | bias3
    u16* xb  = (u16*)d_ws;
    u16* wtq = xb + (size_t)BS_ * DIM_;
    u16* wtk = wtq + (size_t)DIM_ * DIM_;
    u16* wtv = wtk + (size_t)DIM_ * DIM_;
    u16* wto = wtv + (size_t)DIM_ * DIM_;
    u16* qws = wto + (size_t)DIM_ * DIM_;
    u16* kws = qws + BHSD;
    u16* vtw = kws + BHSD;
    float* bias3 = (float*)(vtw + BHSD);

    const dim3 blk(256);

    cvt_x<<<dim3(BS_ * DIM_ / 8 / 256), blk, 0, stream>>>(x, xb);
    wtrans4<<<dim3(32, 32, 4), blk, 0, stream>>>(Wq, Wk, Wv, Wo, wtq, wtk, wtv, wto);
    cat_bias<<<dim3(12), blk, 0, stream>>>(bq, bk, bv, bias3);

    // fused QKV projection: q,k head-major; V written transposed+permuted
    gemm_mfma<128, 0, 0><<<dim3(32, 24), blk, 0, stream>>>(xb, wtq, bias3, qws);

    rope2<<<dim3(B_ * H_ * S_ / 8, 1, 2), blk, 0, stream>>>(qws, kws, theta);

    // bh-fast grid: XCD = bh % 8 -> KV L2-resident per XCD
    attn_mfma<<<dim3(32, 16), blk, 0, stream>>>(qws, kws, vtw);

    // output projection (head-major A in, fp32 row-major out)
    gemm_mfma<64, 1, 1><<<dim3(32, 16), blk, 0, stream>>>(qws, wto, bo, out);
}

// Round 7
// 116.329 us; speedup vs baseline: 1.9176x; 1.0979x over previous
//
#include <hip/hip_runtime.h>
#include <math.h>

#define B_   2
#define S_   2048
#define DIM_ 1024
#define H_   16
#define HD_  64
#define BS_  (B_ * S_)              // 4096
#define BHSD ((size_t)B_ * H_ * S_ * HD_)   // 4M elements
#define CEXP 0.1803368801111244f    // log2(e) / sqrt(64)

typedef unsigned short u16;
typedef unsigned int   u32;
typedef short s16x8 __attribute__((ext_vector_type(8)));
typedef float f32x4 __attribute__((ext_vector_type(4)));

#define MFMA16(a, b, c) __builtin_amdgcn_mfma_f32_16x16x32_bf16((a), (b), (c), 0, 0, 0)

__device__ __forceinline__ u16 f2bf(float f) {
    u32 u = __float_as_uint(f);
    u += 0x7fffu + ((u >> 16) & 1u);            // RNE
    return (u16)(u >> 16);
}
__device__ __forceinline__ float bf2f(u16 h) {
    return __uint_as_float(((u32)h) << 16);
}
__device__ __forceinline__ u32 cvt_pk_bf16(float a, float b) {
    u32 r;
    asm("v_cvt_pk_bf16_f32 %0, %1, %2" : "=v"(r) : "v"(a), "v"(b));
    return r;
}
// async global->LDS, 16B/lane; LDS dest = wave-uniform base + lane*16
__device__ __forceinline__ void gl16(void* lds, const void* g) {
    __builtin_amdgcn_global_load_lds(
        (__attribute__((address_space(1))) void*)(g),
        (__attribute__((address_space(3))) void*)(lds), 16, 0, 0);
}

// ---------------------------------------------------------------------------
// x (fp32, 4096x1024) -> bf16
// ---------------------------------------------------------------------------
__global__ __launch_bounds__(256) void cvt_x(const float* __restrict__ X,
                                             u16* __restrict__ Y)
{
    const int i = blockIdx.x * 256 + threadIdx.x;
    const float4 a = *(const float4*)(X + (size_t)i * 8);
    const float4 b = *(const float4*)(X + (size_t)i * 8 + 4);
    s16x8 o;
    o[0] = (short)f2bf(a.x); o[1] = (short)f2bf(a.y);
    o[2] = (short)f2bf(a.z); o[3] = (short)f2bf(a.w);
    o[4] = (short)f2bf(b.x); o[5] = (short)f2bf(b.y);
    o[6] = (short)f2bf(b.z); o[7] = (short)f2bf(b.w);
    *(s16x8*)(Y + (size_t)i * 8) = o;
}

// ---------------------------------------------------------------------------
// W (fp32 [K][N]) -> Wt (bf16 [N][K]); z selects weight. 32x32 LDS transpose.
// ---------------------------------------------------------------------------
__global__ __launch_bounds__(256) void wtrans4(
    const float* __restrict__ W0, const float* __restrict__ W1,
    const float* __restrict__ W2, const float* __restrict__ W3,
    u16* __restrict__ T0, u16* __restrict__ T1,
    u16* __restrict__ T2, u16* __restrict__ T3)
{
    const float* W; u16* T;
    switch (blockIdx.z) {
        case 0: W = W0; T = T0; break;
        case 1: W = W1; T = T1; break;
        case 2: W = W2; T = T2; break;
        default: W = W3; T = T3; break;
    }
    __shared__ float tile[32][33];
    const int n0 = blockIdx.x * 32, k0 = blockIdx.y * 32;
    const int c = threadIdx.x & 31, rr = threadIdx.x >> 5;
#pragma unroll
    for (int i = 0; i < 4; ++i) {
        const int k = rr + i * 8;
        tile[k][c] = W[(size_t)(k0 + k) * DIM_ + n0 + c];
    }
    __syncthreads();
#pragma unroll
    for (int i = 0; i < 4; ++i) {
        const int n = rr + i * 8;
        T[(size_t)(n0 + n) * DIM_ + k0 + c] = f2bf(tile[c][n]);
    }
}

// ---------------------------------------------------------------------------
// concat biases: bias3[0:1024)=bq, [1024:2048)=bk, [2048:3072)=bv
// ---------------------------------------------------------------------------
__global__ __launch_bounds__(256) void cat_bias(
    const float* __restrict__ q, const float* __restrict__ k,
    const float* __restrict__ v, float* __restrict__ o)
{
    const int i = blockIdx.x * 256 + threadIdx.x;   // grid 12 -> 3072
    o[i] = (i < 1024) ? q[i] : ((i < 2048) ? k[i - 1024] : v[i - 2048]);
}

// ---------------------------------------------------------------------------
// bf16 MFMA GEMM, tile 128 x BN, BK=64, 256 threads (4 waves, 2x2 quadrants).
// A,Bt staged via global_load_lds (16B) into linear LDS, XOR-swizzled via
// pre-swizzled global source.
// EPI 0: bf16 head-major out into q|k|VT. VT = V transposed with kv-bit
//        permutation pi: bits [5,4,3,2] -> [2,5,4,3] within each 64-block
//        (makes the attention PV A-fragment lane-local).
// EPI 1: fp32 row-major out.
// ---------------------------------------------------------------------------
template<int BN, int HMIN, int EPI>
__global__ __launch_bounds__(256, 3) void gemm_mfma(
    const u16* __restrict__ A, const u16* __restrict__ Bt,
    const float* __restrict__ bias, void* __restrict__ Yv)
{
    __shared__ u16 As[128 * 64];
    __shared__ u16 Bs[BN * 64];

    const int tid = threadIdx.x, lane = tid & 63, wid = tid >> 6;
    const int l15 = lane & 15, lg = lane >> 4;
    const int row0 = blockIdx.x * 128, col0 = blockIdx.y * BN;
    const int wr = (wid >> 1) * 64;
    const int wc = (wid & 1) * (BN / 2);
    constexpr int NM = 4, NN = BN / 32, BCH = BN / 32;

    const int l8 = lane >> 3, l7 = lane & 7;
    const int colE = ((l7 ^ l8) << 3);          // k-element offset (swizzled)

    const u16* aptr[4]; u16* aldp[4];
#pragma unroll
    for (int i = 0; i < 4; ++i) {
        const int ci = wid * 4 + i;
        const int rr = row0 + ci * 8 + l8;
        size_t a0;
        if (HMIN)
            a0 = (((size_t)(rr >> 11) * H_) * S_ + (rr & (S_ - 1))) * HD_ + colE;
        else
            a0 = (size_t)rr * DIM_ + colE;
        aptr[i] = A + a0;
        aldp[i] = As + ci * 512;
    }
    const u16* bptr[BCH]; u16* bldp[BCH];
#pragma unroll
    for (int i = 0; i < BCH; ++i) {
        const int ci = wid * BCH + i;
        const int rr = col0 + ci * 8 + l8;
        bptr[i] = Bt + (size_t)rr * DIM_ + colE;
        bldp[i] = Bs + ci * 512;
    }
    const size_t astep = HMIN ? (size_t)S_ * HD_ : 64;

    f32x4 acc[NM][NN];
#pragma unroll
    for (int m = 0; m < NM; ++m)
#pragma unroll
        for (int n = 0; n < NN; ++n) acc[m][n] = (f32x4){0.f, 0.f, 0.f, 0.f};

    for (int k0 = 0; k0 < DIM_; k0 += 64) {
        __syncthreads();   // previous frag reads done
#pragma unroll
        for (int i = 0; i < 4; ++i) gl16(aldp[i], aptr[i]);
#pragma unroll
        for (int i = 0; i < BCH; ++i) gl16(bldp[i], bptr[i]);
#pragma unroll
        for (int i = 0; i < 4; ++i) aptr[i] += astep;
#pragma unroll
        for (int i = 0; i < BCH; ++i) bptr[i] += 64;
        __syncthreads();   // loads drained

        s16x8 af[NM][2], bfr[NN][2];
#pragma unroll
        for (int m = 0; m < NM; ++m) {
            const int row = wr + m * 16 + l15;
#pragma unroll
            for (int kf = 0; kf < 2; ++kf)
                af[m][kf] = *(const s16x8*)&As[row * 64 +
                    (((kf * 64 + lg * 16) ^ ((l15 & 7) << 4)) >> 1)];
        }
#pragma unroll
        for (int n = 0; n < NN; ++n) {
            const int row = wc + n * 16 + l15;
#pragma unroll
            for (int kf = 0; kf < 2; ++kf)
                bfr[n][kf] = *(const s16x8*)&Bs[row * 64 +
                    (((kf * 64 + lg * 16) ^ ((l15 & 7) << 4)) >> 1)];
        }
        __builtin_amdgcn_s_setprio(1);
#pragma unroll
        for (int m = 0; m < NM; ++m)
#pragma unroll
            for (int n = 0; n < NN; ++n) {
                acc[m][n] = MFMA16(af[m][0], bfr[n][0], acc[m][n]);
                acc[m][n] = MFMA16(af[m][1], bfr[n][1], acc[m][n]);
            }
        __builtin_amdgcn_s_setprio(0);
    }

    // epilogue
#pragma unroll
    for (int n = 0; n < NN; ++n) {
        const int cc = col0 + wc + n * 16 + l15;
        const float bv = bias[cc];
#pragma unroll
        for (int m = 0; m < NM; ++m)
#pragma unroll
            for (int r = 0; r < 4; ++r) {
                const int rr = row0 + wr + m * 16 + lg * 4 + r;
                const float val = acc[m][n][r] + bv;
                if (EPI == 0) {
                    u16* Y = (u16*)Yv;
                    const int which = cc >> 10, hh = (cc >> 6) & (H_ - 1), d = cc & 63;
                    const int b = rr >> 11, s = rr & (S_ - 1);
                    size_t dst;
                    if (which == 2) {
                        // V^T with kv permutation pi within each 64-block:
                        // bits {2,3}->{3,4}, {4}->{5}, {5}->{2}
                        const int sp = (s & ~60) | ((s & 12) << 1)
                                     | ((s & 16) << 1) | ((s & 32) >> 3);
                        dst = 2 * BHSD + ((size_t)(b * H_ + hh) * HD_ + d) * S_ + sp;
                    } else {
                        dst = (size_t)which * BHSD
                            + (((size_t)b * H_ + hh) * S_ + s) * HD_ + d;
                    }
                    Y[dst] = f2bf(val);
                } else {
                    ((float*)Yv)[(size_t)rr * DIM_ + cc] = val;
                }
            }
    }
}

// ---------------------------------------------------------------------------
// RoPE in place on bf16 [B*H][S][64]; z=0: q (pre-scaled by log2(e)/8), z=1: k.
// ---------------------------------------------------------------------------
__global__ __launch_bounds__(256) void rope2(u16* __restrict__ Tq, u16* __restrict__ Tk,
                                             const float* __restrict__ theta)
{
    u16* T = blockIdx.z ? Tk : Tq;
    const float scl = blockIdx.z ? 1.0f : CEXP;
    const int row = blockIdx.x * 8 + (threadIdx.x >> 5);
    const int j   = threadIdx.x & 31;
    const int s   = row & (S_ - 1);
    u16* rp = T + (size_t)row * HD_;
    const u32 pr = *(const u32*)(rp + 2 * j);
    const float x1 = bf2f((u16)(pr & 0xffffu));
    const float x2 = bf2f((u16)(pr >> 16));
    float sn, cs;
    sincosf((float)s * theta[j], &sn, &cs);
    const u16 o1 = f2bf((x1 * cs - x2 * sn) * scl);
    const u16 o2 = f2bf((x1 * sn + x2 * cs) * scl);
    rp[j]      = o1;    // wave-internal: loads complete before stores
    rp[32 + j] = o2;
}

// ---------------------------------------------------------------------------
// Causal flash attention, balanced pairs. Grid (32 bh FAST, 16 pairs) = 512
// blocks, 2/CU. Block processes q-tile qtA = pidx then qtB = 31-pidx
// (64 rows each; 4 waves x 16 rows, MFMA16, swapped QK^T). KV staged in
// 128-kv steps, double-buffered via global_load_lds with XOR swizzle;
// every block runs exactly 17 stage-steps (33 kv-64-tiles). Q pre-scaled
// by log2(e)/8; V^T pi-permuted -> lane-local PV fragments. In-place out.
// ---------------------------------------------------------------------------
__global__ __launch_bounds__(256, 2) void attn_pair(
    u16* __restrict__ Q, const u16* __restrict__ K, const u16* __restrict__ VT)
{
    const int bh   = blockIdx.x;
    const int pidx = blockIdx.y;              // 0..15
    const int stA  = (pidx >> 1) + 1;         // steps in phase A

    u16* Qg = Q + (size_t)bh * S_ * HD_;
    const u16* Kg = K + (size_t)bh * S_ * HD_;
    const u16* Vg = VT + (size_t)bh * HD_ * S_;   // pi-permuted [64][2048]

    __shared__ u16 Ks[2][128 * 64];   // 2 x 16 KB
    __shared__ u16 Vs[2][64 * 128];   // 2 x 16 KB

    const int tid = threadIdx.x, wid = tid >> 6, lane = tid & 63;
    const int l15 = lane & 15, lg = lane >> 4;
    const int srow = lane >> 3, sslt = lane & 7;      // K staging coords
    const int vrow = lane >> 4, vslt = lane & 15;     // V staging coords

    auto stage = [&](int bufi, int j0) {
#pragma unroll
        for (int i = 0; i < 4; ++i) {
            const int grp = wid * 4 + i;                      // 0..15
            const int kr  = grp * 8 + srow;                   // K row 0..127
            gl16(&Ks[bufi][grp * 512],
                 Kg + (size_t)(j0 + kr) * HD_ + ((sslt ^ (kr & 7)) << 3));
            const int d = grp * 4 + vrow;                     // V row 0..63
            gl16(&Vs[bufi][grp * 512],
                 Vg + (size_t)d * S_ + j0 + ((vslt ^ (d & 15)) << 3));
        }
    };

    stage(0, 0);
    __syncthreads();   // vmcnt(0) drained before barrier

    int buf = 0, g = 0;
#pragma unroll
    for (int phase = 0; phase < 2; ++phase) {
        const int qt = phase ? (31 - pidx) : pidx;   // 64-row q-tile index
        const int st = (qt >> 1) + 1;                // 128-kv steps this phase
        const int q0 = qt * 64 + wid * 16;           // wave's first q row

        // Q fragments: rows q0 + l15, halves lg*8 + {0,32} (pre-scaled)
        s16x8 qf[2];
        {
            const u16* qrow = Qg + (size_t)(q0 + l15) * HD_ + lg * 8;
            qf[0] = *(const s16x8*)(qrow);
            qf[1] = *(const s16x8*)(qrow + 32);
        }

        f32x4 o[4];
#pragma unroll
        for (int n = 0; n < 4; ++n) o[n] = (f32x4){0.f, 0.f, 0.f, 0.f};
        float mI = -1e30f, lI = 0.f;

        for (int s = 0; s < st; ++s, ++g) {
            if (g + 1 < 17) {                 // prefetch next step
                const int nl = (g + 1 >= stA) ? (g + 1 - stA) : (g + 1);
                stage(buf ^ 1, nl * 128);
            }
            const u16* Kb = Ks[buf];
            const u16* Vb = Vs[buf];
            const int kvlim = (s == st - 1 && !(qt & 1)) ? 64 : 128;

#pragma unroll
            for (int h64 = 0; h64 < 2; ++h64) {
                if (h64 * 64 < kvlim) {
                    const bool diag = (s == st - 1) && (h64 == (qt & 1));

                    // ---- swapped QK^T (16x16): sc[sub][r] =
                    //      S[kv = h64*64 + sub*16 + lg*4 + r][q = q0+l15]
                    f32x4 sc[4];
                    __builtin_amdgcn_s_setprio(1);
#pragma unroll
                    for (int sub = 0; sub < 4; ++sub) {
                        const int kr = h64 * 64 + sub * 16 + l15;
                        const s16x8 kf0 = *(const s16x8*)&Kb[kr * 64 +
                            ((lg ^ (kr & 7)) << 3)];
                        const s16x8 kf1 = *(const s16x8*)&Kb[kr * 64 +
                            (((lg + 4) ^ (kr & 7)) << 3)];
                        f32x4 z = (f32x4){0.f, 0.f, 0.f, 0.f};
                        z = MFMA16(kf0, qf[0], z);
                        sc[sub] = MFMA16(kf1, qf[1], z);
                    }
                    __builtin_amdgcn_s_setprio(0);

                    if (diag) {     // diagonal 64-tile: aligned 16x16 subs
#pragma unroll
                        for (int sub = 0; sub < 4; ++sub) {
                            if (sub == wid) {
#pragma unroll
                                for (int r = 0; r < 4; ++r)
                                    if (lg * 4 + r > l15) sc[sub][r] = -1e30f;
                            } else if (sub > wid) {
#pragma unroll
                                for (int r = 0; r < 4; ++r) sc[sub][r] = -1e30f;
                            }
                        }
                    }

                    // ---- online softmax (log2 domain, defer-max THR=8)
                    float pm = -1e30f;
#pragma unroll
                    for (int sub = 0; sub < 4; ++sub)
#pragma unroll
                        for (int r = 0; r < 4; ++r) pm = fmaxf(pm, sc[sub][r]);
                    pm = fmaxf(pm, __shfl_xor(pm, 16));
                    pm = fmaxf(pm, __shfl_xor(pm, 32));
                    if (!__all(pm - mI <= 8.f)) {
                        const float mn = fmaxf(mI, pm);
                        const float al = __builtin_amdgcn_exp2f(mI - mn);
                        mI = mn; lI *= al;
#pragma unroll
                        for (int r = 0; r < 4; ++r) {
                            const float at = __shfl(al, lg * 4 + r);
#pragma unroll
                            for (int n = 0; n < 4; ++n) o[n][r] *= at;
                        }
                    }
                    float p[4][4];
                    float ps = 0.f;
#pragma unroll
                    for (int sub = 0; sub < 4; ++sub)
#pragma unroll
                        for (int r = 0; r < 4; ++r) {
                            p[sub][r] = __builtin_amdgcn_exp2f(sc[sub][r] - mI);
                            ps += p[sub][r];
                        }
                    ps += __shfl_xor(ps, 16);
                    ps += __shfl_xor(ps, 32);
                    lI += ps;

                    // ---- PV: lane-local A-fragments (pi-permuted V^T)
                    union { s16x8 v; u32 w[4]; } af[2];
#pragma unroll
                    for (int step = 0; step < 2; ++step)
#pragma unroll
                        for (int jj = 0; jj < 4; ++jj) {
                            const int sub = (jj >> 1) * 2 + step;
                            const int r0  = (jj & 1) * 2;
                            af[step].w[jj] = cvt_pk_bf16(p[sub][r0], p[sub][r0 + 1]);
                        }
                    __builtin_amdgcn_s_setprio(1);
#pragma unroll
                    for (int n = 0; n < 4; ++n) {
                        const int d = n * 16 + l15;
                        const s16x8 vf0 = *(const s16x8*)&Vb[d * 128 +
                            (((h64 * 8 + lg) ^ (d & 15)) << 3)];
                        const s16x8 vf1 = *(const s16x8*)&Vb[d * 128 +
                            (((h64 * 8 + lg + 4) ^ (d & 15)) << 3)];
                        o[n] = MFMA16(af[0].v, vf0, o[n]);
                        o[n] = MFMA16(af[1].v, vf1, o[n]);
                    }
                    __builtin_amdgcn_s_setprio(0);
                }
            }

            __syncthreads();   // drains prefetch; buffer handoff
            buf ^= 1;
        }

        // ---- phase epilogue: O / l, write bf16 in place into Q
        const float il = 1.f / lI;
        u16* orow = Qg + (size_t)(qt * 64 + wid * 16 + lg * 4) * HD_ + l15;
#pragma unroll
        for (int r = 0; r < 4; ++r) {
            const float ilr = __shfl(il, lg * 4 + r);
#pragma unroll
            for (int n = 0; n < 4; ++n)
                orow[r * HD_ + n * 16] = f2bf(o[n][r] * ilr);
        }
    }
}

// ---------------------------------------------------------------------------
extern "C" void kernel_launch(void* const* d_in, const int* in_sizes, int n_in,
                              void* d_out, int out_size, void* d_ws, size_t ws_size,
                              hipStream_t stream)
{
    (void)in_sizes; (void)n_in; (void)out_size; (void)ws_size;
    const float* x     = (const float*)d_in[0];
    const float* theta = (const float*)d_in[2];
    const float* Wq    = (const float*)d_in[3];
    const float* bq    = (const float*)d_in[4];
    const float* Wk    = (const float*)d_in[5];
    const float* bk    = (const float*)d_in[6];
    const float* Wv    = (const float*)d_in[7];
    const float* bv    = (const float*)d_in[8];
    const float* Wo    = (const float*)d_in[9];
    const float* bo    = (const float*)d_in[10];
    float* out = (float*)d_out;

    // ws (u16): xb 4M | wtq|wtk|wtv 3M | wto 1M | q 4M | k 4M | VT 4M | bias3
    u16* xb  = (u16*)d_ws;
    u16* wtq = xb + (size_t)BS_ * DIM_;
    u16* wtk = wtq + (size_t)DIM_ * DIM_;
    u16* wtv = wtk + (size_t)DIM_ * DIM_;
    u16* wto = wtv + (size_t)DIM_ * DIM_;
    u16* qws = wto + (size_t)DIM_ * DIM_;
    u16* kws = qws + BHSD;
    u16* vtw = kws + BHSD;
    float* bias3 = (float*)(vtw + BHSD);

    const dim3 blk(256);

    cvt_x<<<dim3(BS_ * DIM_ / 8 / 256), blk, 0, stream>>>(x, xb);
    wtrans4<<<dim3(32, 32, 4), blk, 0, stream>>>(Wq, Wk, Wv, Wo, wtq, wtk, wtv, wto);
    cat_bias<<<dim3(12), blk, 0, stream>>>(bq, bk, bv, bias3);

    // fused QKV projection: q,k head-major; V written transposed+pi-permuted
    gemm_mfma<128, 0, 0><<<dim3(32, 24), blk, 0, stream>>>(xb, wtq, bias3, qws);

    rope2<<<dim3(B_ * H_ * S_ / 8, 1, 2), blk, 0, stream>>>(qws, kws, theta);

    // balanced-pair attention; bh-fast grid keeps each head's KV in one XCD L2
    attn_pair<<<dim3(32, 16), blk, 0, stream>>>(qws, kws, vtw);

    // output projection (head-major A in, fp32 row-major out)
    gemm_mfma<64, 1, 1><<<dim3(32, 16), blk, 0, stream>>>(qws, wto, bo, out);
}

// Round 8
// 101.295 us; speedup vs baseline: 2.2022x; 1.1484x over previous
//
#include <hip/hip_runtime.h>
#include <math.h>

#define B_   2
#define S_   2048
#define DIM_ 1024
#define H_   16
#define HD_  64
#define BS_  (B_ * S_)              // 4096
#define BHSD ((size_t)B_ * H_ * S_ * HD_)   // 4M elements
#define CEXP 0.1803368801111244f    // log2(e) / sqrt(64)

typedef unsigned short u16;
typedef unsigned int   u32;
typedef short s16x8 __attribute__((ext_vector_type(8)));
typedef float f32x4 __attribute__((ext_vector_type(4)));

#define MFMA16(a, b, c) __builtin_amdgcn_mfma_f32_16x16x32_bf16((a), (b), (c), 0, 0, 0)

__device__ __forceinline__ u16 f2bf(float f) {
    u32 u = __float_as_uint(f);
    u += 0x7fffu + ((u >> 16) & 1u);            // RNE
    return (u16)(u >> 16);
}
__device__ __forceinline__ u32 cvt_pk_bf16(float a, float b) {
    u32 r;
    asm("v_cvt_pk_bf16_f32 %0, %1, %2" : "=v"(r) : "v"(a), "v"(b));
    return r;
}
// async global->LDS, 16B/lane; LDS dest must be WAVE-UNIFORM base (+lane*16)
__device__ __forceinline__ void gl16(void* lds, const void* g) {
    __builtin_amdgcn_global_load_lds(
        (__attribute__((address_space(1))) void*)(g),
        (__attribute__((address_space(3))) void*)(lds), 16, 0, 0);
}

// ---------------------------------------------------------------------------
// prep: fused cvt_x | weight transpose (+q/k col-permutation) | cos/sin table
// | bias concat (permuted). Dispatch by blockIdx.x range.
//   [0, 2048)      : x fp32 -> bf16 (8 elems/thread)
//   [2048, 6144)   : W z=idx>>10 transpose 32x32; z<2 get rope col-perm
//   [6144, 6400)   : cs table: cs[s*32+j] = (cos(s*theta[j]), sin(...))
//   [6400, 6412)   : bias3 concat with q/k permutation
// ---------------------------------------------------------------------------
__global__ __launch_bounds__(256) void prep(
    const float* __restrict__ x, u16* __restrict__ xb,
    const float* __restrict__ W0, const float* __restrict__ W1,
    const float* __restrict__ W2, const float* __restrict__ W3,
    u16* __restrict__ T0, u16* __restrict__ T1,
    u16* __restrict__ T2, u16* __restrict__ T3,
    const float* __restrict__ bq, const float* __restrict__ bk,
    const float* __restrict__ bv, float* __restrict__ bias3,
    const float* __restrict__ theta, float2* __restrict__ cs)
{
    __shared__ float tile[32][33];
    const int bid = blockIdx.x, tid = threadIdx.x;

    if (bid < 2048) {                       // ---- x -> bf16
        const int i = bid * 256 + tid;
        const float4 a = *(const float4*)(x + (size_t)i * 8);
        const float4 b = *(const float4*)(x + (size_t)i * 8 + 4);
        s16x8 o;
        o[0] = (short)f2bf(a.x); o[1] = (short)f2bf(a.y);
        o[2] = (short)f2bf(a.z); o[3] = (short)f2bf(a.w);
        o[4] = (short)f2bf(b.x); o[5] = (short)f2bf(b.y);
        o[6] = (short)f2bf(b.z); o[7] = (short)f2bf(b.w);
        *(s16x8*)(xb + (size_t)i * 8) = o;
    } else if (bid < 6144) {                // ---- W transpose
        const int idx = bid - 2048;
        const int z = idx >> 10;
        const float* W; u16* T;
        switch (z) {
            case 0: W = W0; T = T0; break;
            case 1: W = W1; T = T1; break;
            case 2: W = W2; T = T2; break;
            default: W = W3; T = T3; break;
        }
        const int n0 = ((idx >> 5) & 31) * 32, k0 = (idx & 31) * 32;
        const int c = tid & 31, rr = tid >> 5;
#pragma unroll
        for (int i = 0; i < 4; ++i) {
            const int k = rr + i * 8;
            tile[k][c] = W[(size_t)(k0 + k) * DIM_ + n0 + c];
        }
        __syncthreads();
#pragma unroll
        for (int i = 0; i < 4; ++i) {
            const int col = n0 + rr + i * 8;
            int pcol = col;
            if (z < 2) {                    // rope col-perm: even->lo, odd->hi
                const int dd = col & 63;
                const int pd = (dd & 1) ? 32 + (dd >> 1) : (dd >> 1);
                pcol = (col & ~63) | pd;
            }
            T[(size_t)pcol * DIM_ + k0 + c] = f2bf(tile[c][rr + i * 8]);
        }
    } else if (bid < 6400) {                // ---- cos/sin table
        const int idx = bid - 6144;
        const int s = idx * 8 + (tid >> 5), j = tid & 31;
        float sn, cn;
        sincosf((float)s * theta[j], &sn, &cn);
        cs[(s << 5) + j] = make_float2(cn, sn);
    } else {                                // ---- bias concat (permuted q,k)
        const int i = (bid - 6400) * 256 + tid;   // 0..3071
        const int which = i >> 10, local = i & 1023;
        const float v = (which == 0) ? bq[local]
                      : (which == 1) ? bk[local] : bv[local];
        int dst = i;
        if (which < 2) {
            const int dd = local & 63;
            const int pd = (dd & 1) ? 32 + (dd >> 1) : (dd >> 1);
            dst = which * 1024 + (local & ~63) + pd;
        }
        bias3[dst] = v;
    }
}

// ---------------------------------------------------------------------------
// bf16 MFMA GEMM, tile 128 x BN, BK=64, 256 threads (4 waves, 2x2 quadrants).
// A,Bt staged via global_load_lds (16B) into linear LDS, XOR-swizzled via
// pre-swizzled global source.
// EPI 0: bf16 head-major out into q|k|VT.
//   q,k: fused RoPE (weights col-permuted; pairs (n, n+2) in-register) +
//        q pre-scaled by log2(e)/8.
//   VT : V transposed with kv-bit perm pi: bits[5,4,3,2]->[2,5,4,3]
//        (makes the attention PV A-fragment lane-local).
// EPI 1: fp32 row-major out.
// ---------------------------------------------------------------------------
template<int BN, int HMIN, int EPI>
__global__ __launch_bounds__(256, 3) void gemm_mfma(
    const u16* __restrict__ A, const u16* __restrict__ Bt,
    const float* __restrict__ bias, void* __restrict__ Yv,
    const float2* __restrict__ cs)
{
    __shared__ u16 As[128 * 64];
    __shared__ u16 Bs[BN * 64];

    const int tid = threadIdx.x, lane = tid & 63, wid = tid >> 6;
    const int l15 = lane & 15, lg = lane >> 4;
    const int row0 = blockIdx.x * 128, col0 = blockIdx.y * BN;
    const int wr = (wid >> 1) * 64;
    const int wc = (wid & 1) * (BN / 2);
    constexpr int NM = 4, NN = BN / 32, BCH = BN / 32;

    const int l8 = lane >> 3, l7 = lane & 7;
    const int colE = ((l7 ^ l8) << 3);          // k-element offset (swizzled)

    const u16* aptr[4]; u16* aldp[4];
#pragma unroll
    for (int i = 0; i < 4; ++i) {
        const int ci = wid * 4 + i;
        const int rr = row0 + ci * 8 + l8;
        size_t a0;
        if (HMIN)
            a0 = (((size_t)(rr >> 11) * H_) * S_ + (rr & (S_ - 1))) * HD_ + colE;
        else
            a0 = (size_t)rr * DIM_ + colE;
        aptr[i] = A + a0;
        aldp[i] = As + ci * 512;
    }
    const u16* bptr[BCH]; u16* bldp[BCH];
#pragma unroll
    for (int i = 0; i < BCH; ++i) {
        const int ci = wid * BCH + i;
        const int rr = col0 + ci * 8 + l8;
        bptr[i] = Bt + (size_t)rr * DIM_ + colE;
        bldp[i] = Bs + ci * 512;
    }
    const size_t astep = HMIN ? (size_t)S_ * HD_ : 64;

    f32x4 acc[NM][NN];
#pragma unroll
    for (int m = 0; m < NM; ++m)
#pragma unroll
        for (int n = 0; n < NN; ++n) acc[m][n] = (f32x4){0.f, 0.f, 0.f, 0.f};

    for (int k0 = 0; k0 < DIM_; k0 += 64) {
        __syncthreads();   // previous frag reads done
#pragma unroll
        for (int i = 0; i < 4; ++i) gl16(aldp[i], aptr[i]);
#pragma unroll
        for (int i = 0; i < BCH; ++i) gl16(bldp[i], bptr[i]);
#pragma unroll
        for (int i = 0; i < 4; ++i) aptr[i] += astep;
#pragma unroll
        for (int i = 0; i < BCH; ++i) bptr[i] += 64;
        __syncthreads();   // loads drained

        s16x8 af[NM][2], bfr[NN][2];
#pragma unroll
        for (int m = 0; m < NM; ++m) {
            const int row = wr + m * 16 + l15;
#pragma unroll
            for (int kf = 0; kf < 2; ++kf)
                af[m][kf] = *(const s16x8*)&As[row * 64 +
                    (((kf * 64 + lg * 16) ^ ((l15 & 7) << 4)) >> 1)];
        }
#pragma unroll
        for (int n = 0; n < NN; ++n) {
            const int row = wc + n * 16 + l15;
#pragma unroll
            for (int kf = 0; kf < 2; ++kf)
                bfr[n][kf] = *(const s16x8*)&Bs[row * 64 +
                    (((kf * 64 + lg * 16) ^ ((l15 & 7) << 4)) >> 1)];
        }
        __builtin_amdgcn_s_setprio(1);
#pragma unroll
        for (int m = 0; m < NM; ++m)
#pragma unroll
            for (int n = 0; n < NN; ++n) {
                acc[m][n] = MFMA16(af[m][0], bfr[n][0], acc[m][n]);
                acc[m][n] = MFMA16(af[m][1], bfr[n][1], acc[m][n]);
            }
        __builtin_amdgcn_s_setprio(0);
    }

    // ---- epilogue
    if (EPI == 0) {
        u16* Y = (u16*)Yv;
        const int whichq = (col0 + wc) >> 10;          // wave-uniform
        if (whichq < 2) {
            // fused RoPE: pairs (n, n+2); out d = j and j+32
            const float sclw = (whichq == 0) ? CEXP : 1.0f;
#pragma unroll
            for (int n = 0; n < 2; ++n) {
                const int cc0 = col0 + wc + n * 16 + l15;
                const int j = n * 16 + l15;            // 0..31
                const float bv0 = bias[cc0];
                const float bv1 = bias[cc0 + 32];
                const int hh = (cc0 >> 6) & (H_ - 1);
#pragma unroll
                for (int m = 0; m < NM; ++m)
#pragma unroll
                    for (int r = 0; r < 4; ++r) {
                        const int rr = row0 + wr + m * 16 + lg * 4 + r;
                        const int b = rr >> 11, s = rr & (S_ - 1);
                        const float2 csv = cs[(s << 5) + j];
                        const float v0 = acc[m][n][r] + bv0;
                        const float v1 = acc[m][n + 2][r] + bv1;
                        const size_t base = (size_t)whichq * BHSD
                            + (((size_t)b * H_ + hh) * S_ + s) * HD_;
                        Y[base + j]      = f2bf((v0 * csv.x - v1 * csv.y) * sclw);
                        Y[base + j + 32] = f2bf((v0 * csv.y + v1 * csv.x) * sclw);
                    }
            }
        } else {
#pragma unroll
            for (int n = 0; n < NN; ++n) {
                const int cc = col0 + wc + n * 16 + l15;
                const float bv = bias[cc];
                const int hh = (cc >> 6) & (H_ - 1), d = cc & 63;
#pragma unroll
                for (int m = 0; m < NM; ++m)
#pragma unroll
                    for (int r = 0; r < 4; ++r) {
                        const int rr = row0 + wr + m * 16 + lg * 4 + r;
                        const int b = rr >> 11, s = rr & (S_ - 1);
                        // V^T with kv perm pi: bits {2,3}->{3,4}, {4}->{5}, {5}->{2}
                        const int sp = (s & ~60) | ((s & 12) << 1)
                                     | ((s & 16) << 1) | ((s & 32) >> 3);
                        Y[2 * BHSD + ((size_t)(b * H_ + hh) * HD_ + d) * S_ + sp] =
                            f2bf(acc[m][n][r] + bv);
                    }
            }
        }
    } else {
#pragma unroll
        for (int n = 0; n < NN; ++n) {
            const int cc = col0 + wc + n * 16 + l15;
            const float bv = bias[cc];
#pragma unroll
            for (int m = 0; m < NM; ++m)
#pragma unroll
                for (int r = 0; r < 4; ++r) {
                    const int rr = row0 + wr + m * 16 + lg * 4 + r;
                    ((float*)Yv)[(size_t)rr * DIM_ + cc] = acc[m][n][r] + bv;
                }
        }
    }
}

// ---------------------------------------------------------------------------
// Causal flash attention, 512 threads = 8 waves. Grid (32 bh FAST, 16 pairs).
// Waves 0-3 own q-tile qtA = pidx (16 rows each); waves 4-7 own qtB =
// 31-pidx. One shared 64-kv double-buffered K/V staging (32 KB LDS), steps
// t = 0..31-pidx; per-block compute is constant (33 wave-group-tiles) so
// blocks are balanced. Swapped QK^T MFMA16, log2-domain defer-max softmax,
// pi-permuted V^T -> lane-local PV fragments. Output in place into Q.
// ---------------------------------------------------------------------------
__global__ __launch_bounds__(512, 2) void attn_bal(
    u16* __restrict__ Q, const u16* __restrict__ K, const u16* __restrict__ VT)
{
    const int bh   = blockIdx.x;
    const int pidx = blockIdx.y;              // 0..15
    const int nsteps = 32 - pidx;

    u16* Qg = Q + (size_t)bh * S_ * HD_;
    const u16* Kg = K + (size_t)bh * S_ * HD_;
    const u16* Vg = VT + (size_t)bh * HD_ * S_;   // pi-permuted [64][2048]

    __shared__ u16 Ks[2][64 * 64];   // 2 x 8 KB
    __shared__ u16 Vs[2][64 * 64];   // 2 x 8 KB

    const int tid = threadIdx.x;
    const int w = tid >> 6, lane = tid & 63;
    const int grp = w >> 2, widq = w & 3;
    const int qt = grp ? (31 - pidx) : pidx;  // this wave's 64-row q-tile
    const int myTiles = qt + 1;               // active while t < myTiles
    const int q0 = qt * 64 + widq * 16;
    const int l15 = lane & 15, lg = lane >> 4;

    // staging: each thread 16B of K + 16B of V; LDS base wave-uniform
    const int srow = w * 8 + (lane >> 3);     // 0..63 (K row / V d-row)
    const int sslt = lane & 7;
    const int soff = ((sslt ^ (srow & 7)) << 3);

    auto stage = [&](int bufi, int j0) {
        gl16(&Ks[bufi][w * 512], Kg + (size_t)(j0 + srow) * HD_ + soff);
        gl16(&Vs[bufi][w * 512], Vg + (size_t)srow * S_ + j0 + soff);
    };

    // Q fragments: rows q0 + l15 (rope'd, q pre-scaled by log2(e)/8)
    s16x8 qf[2];
    {
        const u16* qrow = Qg + (size_t)(q0 + l15) * HD_ + lg * 8;
        qf[0] = *(const s16x8*)(qrow);
        qf[1] = *(const s16x8*)(qrow + 32);
    }

    f32x4 o[4];
#pragma unroll
    for (int n = 0; n < 4; ++n) o[n] = (f32x4){0.f, 0.f, 0.f, 0.f};
    float mI = -1e30f, lI = 0.f;

    stage(0, 0);
    __syncthreads();

    int buf = 0;
    for (int t = 0; t < nsteps; ++t) {
        if (t + 1 < nsteps) stage(buf ^ 1, (t + 1) * 64);   // prefetch

        if (t < myTiles) {
            const u16* Kb = Ks[buf];
            const u16* Vb = Vs[buf];

            // ---- swapped QK^T: sc[sub][r] = S[kv=t*64+sub*16+lg*4+r][q0+l15]
            f32x4 sc[4];
            __builtin_amdgcn_s_setprio(1);
#pragma unroll
            for (int sub = 0; sub < 4; ++sub) {
                const int kr = sub * 16 + l15;
                const s16x8 kf0 = *(const s16x8*)&Kb[kr * 64 + ((lg ^ (kr & 7)) << 3)];
                const s16x8 kf1 = *(const s16x8*)&Kb[kr * 64 + (((lg + 4) ^ (kr & 7)) << 3)];
                f32x4 z = (f32x4){0.f, 0.f, 0.f, 0.f};
                z = MFMA16(kf0, qf[0], z);
                sc[sub] = MFMA16(kf1, qf[1], z);
            }
            __builtin_amdgcn_s_setprio(0);

            if (t == qt) {      // diagonal 64-tile: aligned 16x16 subs
#pragma unroll
                for (int sub = 0; sub < 4; ++sub) {
                    if (sub == widq) {
#pragma unroll
                        for (int r = 0; r < 4; ++r)
                            if (lg * 4 + r > l15) sc[sub][r] = -1e30f;
                    } else if (sub > widq) {
#pragma unroll
                        for (int r = 0; r < 4; ++r) sc[sub][r] = -1e30f;
                    }
                }
            }

            // ---- online softmax (log2 domain, defer-max THR=8)
            float pm = -1e30f;
#pragma unroll
            for (int sub = 0; sub < 4; ++sub)
#pragma unroll
                for (int r = 0; r < 4; ++r) pm = fmaxf(pm, sc[sub][r]);
            pm = fmaxf(pm, __shfl_xor(pm, 16));
            pm = fmaxf(pm, __shfl_xor(pm, 32));
            if (!__all(pm - mI <= 8.f)) {
                const float mn = fmaxf(mI, pm);
                const float al = __builtin_amdgcn_exp2f(mI - mn);
                mI = mn; lI *= al;
#pragma unroll
                for (int r = 0; r < 4; ++r) {
                    const float at = __shfl(al, lg * 4 + r);
#pragma unroll
                    for (int n = 0; n < 4; ++n) o[n][r] *= at;
                }
            }
            float p[4][4];
            float ps = 0.f;
#pragma unroll
            for (int sub = 0; sub < 4; ++sub)
#pragma unroll
                for (int r = 0; r < 4; ++r) {
                    p[sub][r] = __builtin_amdgcn_exp2f(sc[sub][r] - mI);
                    ps += p[sub][r];
                }
            ps += __shfl_xor(ps, 16);
            ps += __shfl_xor(ps, 32);
            lI += ps;

            // ---- PV: lane-local A-fragments (pi-permuted V^T)
            union { s16x8 v; u32 w4[4]; } af[2];
#pragma unroll
            for (int step = 0; step < 2; ++step)
#pragma unroll
                for (int jj = 0; jj < 4; ++jj) {
                    const int sub = (jj >> 1) * 2 + step;
                    const int r0  = (jj & 1) * 2;
                    af[step].w4[jj] = cvt_pk_bf16(p[sub][r0], p[sub][r0 + 1]);
                }
            __builtin_amdgcn_s_setprio(1);
#pragma unroll
            for (int n = 0; n < 4; ++n) {
                const int d = n * 16 + l15;
                const s16x8 vf0 = *(const s16x8*)&Vb[d * 64 + ((lg ^ (d & 7)) << 3)];
                const s16x8 vf1 = *(const s16x8*)&Vb[d * 64 + (((lg + 4) ^ (d & 7)) << 3)];
                o[n] = MFMA16(af[0].v, vf0, o[n]);
                o[n] = MFMA16(af[1].v, vf1, o[n]);
            }
            __builtin_amdgcn_s_setprio(0);
        }

        __syncthreads();   // drains prefetch; buffer handoff
        buf ^= 1;
    }

    // ---- epilogue: O / l, write bf16 in place into Q (own 16 rows)
    const float il = 1.f / lI;
    u16* orow = Qg + (size_t)(q0 + lg * 4) * HD_ + l15;
#pragma unroll
    for (int r = 0; r < 4; ++r) {
        const float ilr = __shfl(il, lg * 4 + r);
#pragma unroll
        for (int n = 0; n < 4; ++n)
            orow[r * HD_ + n * 16] = f2bf(o[n][r] * ilr);
    }
}

// ---------------------------------------------------------------------------
extern "C" void kernel_launch(void* const* d_in, const int* in_sizes, int n_in,
                              void* d_out, int out_size, void* d_ws, size_t ws_size,
                              hipStream_t stream)
{
    (void)in_sizes; (void)n_in; (void)out_size; (void)ws_size;
    const float* x     = (const float*)d_in[0];
    const float* theta = (const float*)d_in[2];
    const float* Wq    = (const float*)d_in[3];
    const float* bq    = (const float*)d_in[4];
    const float* Wk    = (const float*)d_in[5];
    const float* bk    = (const float*)d_in[6];
    const float* Wv    = (const float*)d_in[7];
    const float* bv    = (const float*)d_in[8];
    const float* Wo    = (const float*)d_in[9];
    const float* bo    = (const float*)d_in[10];
    float* out = (float*)d_out;

    // ws (u16): xb 4M | wtq|wtk|wtv 3M | wto 1M | q 4M | k 4M | VT 4M |
    //           bias3 (3072 f32, padded to 4096) | cs table (2048x32 float2)
    u16* xb  = (u16*)d_ws;
    u16* wtq = xb + (size_t)BS_ * DIM_;
    u16* wtk = wtq + (size_t)DIM_ * DIM_;
    u16* wtv = wtk + (size_t)DIM_ * DIM_;
    u16* wto = wtv + (size_t)DIM_ * DIM_;
    u16* qws = wto + (size_t)DIM_ * DIM_;
    u16* kws = qws + BHSD;
    u16* vtw = kws + BHSD;
    float* bias3 = (float*)(vtw + BHSD);
    float2* cs = (float2*)(bias3 + 4096);

    // fused prep: cvt_x | wtrans(+perm) | cos/sin table | bias concat(+perm)
    prep<<<dim3(6412), dim3(256), 0, stream>>>(
        x, xb, Wq, Wk, Wv, Wo, wtq, wtk, wtv, wto, bq, bk, bv, bias3, theta, cs);

    // fused QKV projection: q,k rope'd head-major; V transposed+pi-permuted
    gemm_mfma<128, 0, 0><<<dim3(32, 24), dim3(256), 0, stream>>>(
        xb, wtq, bias3, qws, cs);

    // balanced 8-wave attention; bh-fast grid keeps each head's KV in L2
    attn_bal<<<dim3(32, 16), dim3(512), 0, stream>>>(qws, kws, vtw);

    // output projection (head-major A in, fp32 row-major out)
    gemm_mfma<64, 1, 1><<<dim3(32, 16), dim3(256), 0, stream>>>(
        qws, wto, bo, out, cs);
}

// Round 9
// 99.170 us; speedup vs baseline: 2.2494x; 1.0214x over previous
//
#include <hip/hip_runtime.h>
#include <math.h>

#define B_   2
#define S_   2048
#define DIM_ 1024
#define H_   16
#define HD_  64
#define BS_  (B_ * S_)              // 4096
#define BHSD ((size_t)B_ * H_ * S_ * HD_)   // 4M elements
#define CEXP 0.1803368801111244f    // log2(e) / sqrt(64)

typedef unsigned short u16;
typedef unsigned int   u32;
typedef short s16x8 __attribute__((ext_vector_type(8)));
typedef float f32x4 __attribute__((ext_vector_type(4)));

#define MFMA16(a, b, c) __builtin_amdgcn_mfma_f32_16x16x32_bf16((a), (b), (c), 0, 0, 0)

__device__ __forceinline__ u16 f2bf(float f) {
    u32 u = __float_as_uint(f);
    u += 0x7fffu + ((u >> 16) & 1u);            // RNE
    return (u16)(u >> 16);
}
__device__ __forceinline__ u32 cvt_pk_bf16(float a, float b) {
    u32 r;
    asm("v_cvt_pk_bf16_f32 %0, %1, %2" : "=v"(r) : "v"(a), "v"(b));
    return r;
}
// async global->LDS, 16B/lane; LDS dest must be WAVE-UNIFORM base (+lane*16)
__device__ __forceinline__ void gl16(void* lds, const void* g) {
    __builtin_amdgcn_global_load_lds(
        (__attribute__((address_space(1))) void*)(g),
        (__attribute__((address_space(3))) void*)(lds), 16, 0, 0);
}

// ---------------------------------------------------------------------------
// prep: fused cvt_x | weight transpose (+q/k col-permutation) | cos/sin table
// | bias concat (permuted). Dispatch by blockIdx.x range.
//   [0, 2048)      : x fp32 -> bf16 (8 elems/thread)
//   [2048, 6144)   : W z=idx>>10 transpose 32x32; z<2 get rope col-perm
//   [6144, 6400)   : cs table: cs[s*32+j] = (cos(s*theta[j]), sin(...))
//   [6400, 6412)   : bias3 concat with q/k permutation
// ---------------------------------------------------------------------------
__global__ __launch_bounds__(256) void prep(
    const float* __restrict__ x, u16* __restrict__ xb,
    const float* __restrict__ W0, const float* __restrict__ W1,
    const float* __restrict__ W2, const float* __restrict__ W3,
    u16* __restrict__ T0, u16* __restrict__ T1,
    u16* __restrict__ T2, u16* __restrict__ T3,
    const float* __restrict__ bq, const float* __restrict__ bk,
    const float* __restrict__ bv, float* __restrict__ bias3,
    const float* __restrict__ theta, float2* __restrict__ cs)
{
    __shared__ float tile[32][33];
    const int bid = blockIdx.x, tid = threadIdx.x;

    if (bid < 2048) {                       // ---- x -> bf16
        const int i = bid * 256 + tid;
        const float4 a = *(const float4*)(x + (size_t)i * 8);
        const float4 b = *(const float4*)(x + (size_t)i * 8 + 4);
        s16x8 o;
        o[0] = (short)f2bf(a.x); o[1] = (short)f2bf(a.y);
        o[2] = (short)f2bf(a.z); o[3] = (short)f2bf(a.w);
        o[4] = (short)f2bf(b.x); o[5] = (short)f2bf(b.y);
        o[6] = (short)f2bf(b.z); o[7] = (short)f2bf(b.w);
        *(s16x8*)(xb + (size_t)i * 8) = o;
    } else if (bid < 6144) {                // ---- W transpose
        const int idx = bid - 2048;
        const int z = idx >> 10;
        const float* W; u16* T;
        switch (z) {
            case 0: W = W0; T = T0; break;
            case 1: W = W1; T = T1; break;
            case 2: W = W2; T = T2; break;
            default: W = W3; T = T3; break;
        }
        const int n0 = ((idx >> 5) & 31) * 32, k0 = (idx & 31) * 32;
        const int c = tid & 31, rr = tid >> 5;
#pragma unroll
        for (int i = 0; i < 4; ++i) {
            const int k = rr + i * 8;
            tile[k][c] = W[(size_t)(k0 + k) * DIM_ + n0 + c];
        }
        __syncthreads();
#pragma unroll
        for (int i = 0; i < 4; ++i) {
            const int col = n0 + rr + i * 8;
            int pcol = col;
            if (z < 2) {                    // rope col-perm: even->lo, odd->hi
                const int dd = col & 63;
                const int pd = (dd & 1) ? 32 + (dd >> 1) : (dd >> 1);
                pcol = (col & ~63) | pd;
            }
            T[(size_t)pcol * DIM_ + k0 + c] = f2bf(tile[c][rr + i * 8]);
        }
    } else if (bid < 6400) {                // ---- cos/sin table
        const int idx = bid - 6144;
        const int s = idx * 8 + (tid >> 5), j = tid & 31;
        float sn, cn;
        sincosf((float)s * theta[j], &sn, &cn);
        cs[(s << 5) + j] = make_float2(cn, sn);
    } else {                                // ---- bias concat (permuted q,k)
        const int i = (bid - 6400) * 256 + tid;   // 0..3071
        const int which = i >> 10, local = i & 1023;
        const float v = (which == 0) ? bq[local]
                      : (which == 1) ? bk[local] : bv[local];
        int dst = i;
        if (which < 2) {
            const int dd = local & 63;
            const int pd = (dd & 1) ? 32 + (dd >> 1) : (dd >> 1);
            dst = which * 1024 + (local & ~63) + pd;
        }
        bias3[dst] = v;
    }
}

// ---------------------------------------------------------------------------
// bf16 MFMA GEMM, tile 128 x BN, BK=64, 256 threads (4 waves, 2x2 quadrants).
// A,Bt staged via global_load_lds (16B) into linear LDS, XOR-swizzled via
// pre-swizzled global source.
// EPI 0: bf16 head-major out into q|k|VT.
//   q,k: fused RoPE (weights col-permuted; pairs (n, n+2) in-register) +
//        q pre-scaled by log2(e)/8.
//   VT : V transposed with kv-bit perm pi: bits[5,4,3,2]->[2,5,4,3]
//        (makes the attention PV A-fragment lane-local).
// EPI 1: fp32 row-major out.
// ---------------------------------------------------------------------------
template<int BN, int HMIN, int EPI>
__global__ __launch_bounds__(256, 3) void gemm_mfma(
    const u16* __restrict__ A, const u16* __restrict__ Bt,
    const float* __restrict__ bias, void* __restrict__ Yv,
    const float2* __restrict__ cs)
{
    __shared__ u16 As[128 * 64];
    __shared__ u16 Bs[BN * 64];

    const int tid = threadIdx.x, lane = tid & 63, wid = tid >> 6;
    const int l15 = lane & 15, lg = lane >> 4;
    const int row0 = blockIdx.x * 128, col0 = blockIdx.y * BN;
    const int wr = (wid >> 1) * 64;
    const int wc = (wid & 1) * (BN / 2);
    constexpr int NM = 4, NN = BN / 32, BCH = BN / 32;

    const int l8 = lane >> 3, l7 = lane & 7;
    const int colE = ((l7 ^ l8) << 3);          // k-element offset (swizzled)

    const u16* aptr[4]; u16* aldp[4];
#pragma unroll
    for (int i = 0; i < 4; ++i) {
        const int ci = wid * 4 + i;
        const int rr = row0 + ci * 8 + l8;
        size_t a0;
        if (HMIN)
            a0 = (((size_t)(rr >> 11) * H_) * S_ + (rr & (S_ - 1))) * HD_ + colE;
        else
            a0 = (size_t)rr * DIM_ + colE;
        aptr[i] = A + a0;
        aldp[i] = As + ci * 512;
    }
    const u16* bptr[BCH]; u16* bldp[BCH];
#pragma unroll
    for (int i = 0; i < BCH; ++i) {
        const int ci = wid * BCH + i;
        const int rr = col0 + ci * 8 + l8;
        bptr[i] = Bt + (size_t)rr * DIM_ + colE;
        bldp[i] = Bs + ci * 512;
    }
    const size_t astep = HMIN ? (size_t)S_ * HD_ : 64;

    f32x4 acc[NM][NN];
#pragma unroll
    for (int m = 0; m < NM; ++m)
#pragma unroll
        for (int n = 0; n < NN; ++n) acc[m][n] = (f32x4){0.f, 0.f, 0.f, 0.f};

    for (int k0 = 0; k0 < DIM_; k0 += 64) {
        __syncthreads();   // previous frag reads done
#pragma unroll
        for (int i = 0; i < 4; ++i) gl16(aldp[i], aptr[i]);
#pragma unroll
        for (int i = 0; i < BCH; ++i) gl16(bldp[i], bptr[i]);
#pragma unroll
        for (int i = 0; i < 4; ++i) aptr[i] += astep;
#pragma unroll
        for (int i = 0; i < BCH; ++i) bptr[i] += 64;
        __syncthreads();   // loads drained

        s16x8 af[NM][2], bfr[NN][2];
#pragma unroll
        for (int m = 0; m < NM; ++m) {
            const int row = wr + m * 16 + l15;
#pragma unroll
            for (int kf = 0; kf < 2; ++kf)
                af[m][kf] = *(const s16x8*)&As[row * 64 +
                    (((kf * 64 + lg * 16) ^ ((l15 & 7) << 4)) >> 1)];
        }
#pragma unroll
        for (int n = 0; n < NN; ++n) {
            const int row = wc + n * 16 + l15;
#pragma unroll
            for (int kf = 0; kf < 2; ++kf)
                bfr[n][kf] = *(const s16x8*)&Bs[row * 64 +
                    (((kf * 64 + lg * 16) ^ ((l15 & 7) << 4)) >> 1)];
        }
        __builtin_amdgcn_s_setprio(1);
#pragma unroll
        for (int m = 0; m < NM; ++m)
#pragma unroll
            for (int n = 0; n < NN; ++n) {
                acc[m][n] = MFMA16(af[m][0], bfr[n][0], acc[m][n]);
                acc[m][n] = MFMA16(af[m][1], bfr[n][1], acc[m][n]);
            }
        __builtin_amdgcn_s_setprio(0);
    }

    // ---- epilogue
    if (EPI == 0) {
        u16* Y = (u16*)Yv;
        const int whichq = (col0 + wc) >> 10;          // wave-uniform
        if (whichq < 2) {
            // fused RoPE: pairs (n, n+2); out d = j and j+32
            const float sclw = (whichq == 0) ? CEXP : 1.0f;
#pragma unroll
            for (int n = 0; n < 2; ++n) {
                const int cc0 = col0 + wc + n * 16 + l15;
                const int j = n * 16 + l15;            // 0..31
                const float bv0 = bias[cc0];
                const float bv1 = bias[cc0 + 32];
                const int hh = (cc0 >> 6) & (H_ - 1);
#pragma unroll
                for (int m = 0; m < NM; ++m)
#pragma unroll
                    for (int r = 0; r < 4; ++r) {
                        const int rr = row0 + wr + m * 16 + lg * 4 + r;
                        const int b = rr >> 11, s = rr & (S_ - 1);
                        const float2 csv = cs[(s << 5) + j];
                        const float v0 = acc[m][n][r] + bv0;
                        const float v1 = acc[m][n + 2][r] + bv1;
                        const size_t base = (size_t)whichq * BHSD
                            + (((size_t)b * H_ + hh) * S_ + s) * HD_;
                        Y[base + j]      = f2bf((v0 * csv.x - v1 * csv.y) * sclw);
                        Y[base + j + 32] = f2bf((v0 * csv.y + v1 * csv.x) * sclw);
                    }
            }
        } else {
#pragma unroll
            for (int n = 0; n < NN; ++n) {
                const int cc = col0 + wc + n * 16 + l15;
                const float bv = bias[cc];
                const int hh = (cc >> 6) & (H_ - 1), d = cc & 63;
#pragma unroll
                for (int m = 0; m < NM; ++m)
#pragma unroll
                    for (int r = 0; r < 4; ++r) {
                        const int rr = row0 + wr + m * 16 + lg * 4 + r;
                        const int b = rr >> 11, s = rr & (S_ - 1);
                        // V^T with kv perm pi: bits {2,3}->{3,4}, {4}->{5}, {5}->{2}
                        const int sp = (s & ~60) | ((s & 12) << 1)
                                     | ((s & 16) << 1) | ((s & 32) >> 3);
                        Y[2 * BHSD + ((size_t)(b * H_ + hh) * HD_ + d) * S_ + sp] =
                            f2bf(acc[m][n][r] + bv);
                    }
            }
        }
    } else {
#pragma unroll
        for (int n = 0; n < NN; ++n) {
            const int cc = col0 + wc + n * 16 + l15;
            const float bv = bias[cc];
#pragma unroll
            for (int m = 0; m < NM; ++m)
#pragma unroll
                for (int r = 0; r < 4; ++r) {
                    const int rr = row0 + wr + m * 16 + lg * 4 + r;
                    ((float*)Yv)[(size_t)rr * DIM_ + cc] = acc[m][n][r] + bv;
                }
        }
    }
}

// ---------------------------------------------------------------------------
// Causal flash attention: one 64-row q-tile per 256-thread block (4 waves,
// 16 q-rows each, all ACTIVE every step). Grid (32 bh FAST, 32 qt DESC) =
// 1024 blocks, all co-resident (32 KB LDS, 36 VGPR -> 4 blocks/CU = 4
// active waves/SIMD). KV staged 64 rows/step, double-buffered via
// global_load_lds with XOR swizzle. Swapped QK^T MFMA16, log2-domain
// defer-max softmax, pi-permuted V^T -> lane-local PV fragments.
// Output in place into Q.
// ---------------------------------------------------------------------------
__global__ __launch_bounds__(256, 4) void attn_q(
    u16* __restrict__ Q, const u16* __restrict__ K, const u16* __restrict__ VT)
{
    const int bh = blockIdx.x;
    const int qt = 31 - blockIdx.y;           // heavy blocks dispatch first
    const int nsteps = qt + 1;

    u16* Qg = Q + (size_t)bh * S_ * HD_;
    const u16* Kg = K + (size_t)bh * S_ * HD_;
    const u16* Vg = VT + (size_t)bh * HD_ * S_;   // pi-permuted [64][2048]

    __shared__ u16 Ks[2][64 * 64];   // 2 x 8 KB
    __shared__ u16 Vs[2][64 * 64];   // 2 x 8 KB

    const int tid = threadIdx.x;
    const int w = tid >> 6, lane = tid & 63;
    const int q0 = qt * 64 + w * 16;
    const int l15 = lane & 15, lg = lane >> 4;

    // staging: per wave 2 K-chunks + 2 V-chunks (8 rows x 64 cols each)
    const int crow = lane >> 3, cslt = lane & 7;

    auto stage = [&](int bufi, int j0) {
#pragma unroll
        for (int i = 0; i < 2; ++i) {
            const int c = w * 2 + i;                  // chunk 0..7
            const int row = c * 8 + crow;             // 0..63
            const int soff = ((cslt ^ (row & 7)) << 3);
            gl16(&Ks[bufi][c * 512], Kg + (size_t)(j0 + row) * HD_ + soff);
            gl16(&Vs[bufi][c * 512], Vg + (size_t)row * S_ + j0 + soff);
        }
    };

    // Q fragments: rows q0 + l15 (rope'd, q pre-scaled by log2(e)/8)
    s16x8 qf[2];
    {
        const u16* qrow = Qg + (size_t)(q0 + l15) * HD_ + lg * 8;
        qf[0] = *(const s16x8*)(qrow);
        qf[1] = *(const s16x8*)(qrow + 32);
    }

    f32x4 o[4];
#pragma unroll
    for (int n = 0; n < 4; ++n) o[n] = (f32x4){0.f, 0.f, 0.f, 0.f};
    float mI = -1e30f, lI = 0.f;

    stage(0, 0);
    __syncthreads();

    int buf = 0;
    for (int t = 0; t < nsteps; ++t) {
        if (t + 1 < nsteps) stage(buf ^ 1, (t + 1) * 64);   // prefetch

        const u16* Kb = Ks[buf];
        const u16* Vb = Vs[buf];

        // ---- swapped QK^T: sc[sub][r] = S[kv=t*64+sub*16+lg*4+r][q0+l15]
        f32x4 sc[4];
        __builtin_amdgcn_s_setprio(1);
#pragma unroll
        for (int sub = 0; sub < 4; ++sub) {
            const int kr = sub * 16 + l15;
            const s16x8 kf0 = *(const s16x8*)&Kb[kr * 64 + ((lg ^ (kr & 7)) << 3)];
            const s16x8 kf1 = *(const s16x8*)&Kb[kr * 64 + (((lg + 4) ^ (kr & 7)) << 3)];
            f32x4 z = (f32x4){0.f, 0.f, 0.f, 0.f};
            z = MFMA16(kf0, qf[0], z);
            sc[sub] = MFMA16(kf1, qf[1], z);
        }
        __builtin_amdgcn_s_setprio(0);

        if (t == qt) {      // diagonal 64-tile: aligned 16x16 subs
#pragma unroll
            for (int sub = 0; sub < 4; ++sub) {
                if (sub == w) {
#pragma unroll
                    for (int r = 0; r < 4; ++r)
                        if (lg * 4 + r > l15) sc[sub][r] = -1e30f;
                } else if (sub > w) {
#pragma unroll
                    for (int r = 0; r < 4; ++r) sc[sub][r] = -1e30f;
                }
            }
        }

        // ---- online softmax (log2 domain, defer-max THR=8)
        float pm = -1e30f;
#pragma unroll
        for (int sub = 0; sub < 4; ++sub)
#pragma unroll
            for (int r = 0; r < 4; ++r) pm = fmaxf(pm, sc[sub][r]);
        pm = fmaxf(pm, __shfl_xor(pm, 16));
        pm = fmaxf(pm, __shfl_xor(pm, 32));
        if (!__all(pm - mI <= 8.f)) {
            const float mn = fmaxf(mI, pm);
            const float al = __builtin_amdgcn_exp2f(mI - mn);
            mI = mn; lI *= al;
#pragma unroll
            for (int r = 0; r < 4; ++r) {
                const float at = __shfl(al, lg * 4 + r);
#pragma unroll
                for (int n = 0; n < 4; ++n) o[n][r] *= at;
            }
        }
        float p[4][4];
        float ps = 0.f;
#pragma unroll
        for (int sub = 0; sub < 4; ++sub)
#pragma unroll
            for (int r = 0; r < 4; ++r) {
                p[sub][r] = __builtin_amdgcn_exp2f(sc[sub][r] - mI);
                ps += p[sub][r];
            }
        ps += __shfl_xor(ps, 16);
        ps += __shfl_xor(ps, 32);
        lI += ps;

        // ---- PV: lane-local A-fragments (pi-permuted V^T)
        union { s16x8 v; u32 w4[4]; } af[2];
#pragma unroll
        for (int step = 0; step < 2; ++step)
#pragma unroll
            for (int jj = 0; jj < 4; ++jj) {
                const int sub = (jj >> 1) * 2 + step;
                const int r0  = (jj & 1) * 2;
                af[step].w4[jj] = cvt_pk_bf16(p[sub][r0], p[sub][r0 + 1]);
            }
        __builtin_amdgcn_s_setprio(1);
#pragma unroll
        for (int n = 0; n < 4; ++n) {
            const int d = n * 16 + l15;
            const s16x8 vf0 = *(const s16x8*)&Vb[d * 64 + ((lg ^ (d & 7)) << 3)];
            const s16x8 vf1 = *(const s16x8*)&Vb[d * 64 + (((lg + 4) ^ (d & 7)) << 3)];
            o[n] = MFMA16(af[0].v, vf0, o[n]);
            o[n] = MFMA16(af[1].v, vf1, o[n]);
        }
        __builtin_amdgcn_s_setprio(0);

        __syncthreads();   // drains prefetch; buffer handoff
        buf ^= 1;
    }

    // ---- epilogue: O / l, write bf16 in place into Q (own 16 rows)
    const float il = 1.f / lI;
    u16* orow = Qg + (size_t)(q0 + lg * 4) * HD_ + l15;
#pragma unroll
    for (int r = 0; r < 4; ++r) {
        const float ilr = __shfl(il, lg * 4 + r);
#pragma unroll
        for (int n = 0; n < 4; ++n)
            orow[r * HD_ + n * 16] = f2bf(o[n][r] * ilr);
    }
}

// ---------------------------------------------------------------------------
extern "C" void kernel_launch(void* const* d_in, const int* in_sizes, int n_in,
                              void* d_out, int out_size, void* d_ws, size_t ws_size,
                              hipStream_t stream)
{
    (void)in_sizes; (void)n_in; (void)out_size; (void)ws_size;
    const float* x     = (const float*)d_in[0];
    const float* theta = (const float*)d_in[2];
    const float* Wq    = (const float*)d_in[3];
    const float* bq    = (const float*)d_in[4];
    const float* Wk    = (const float*)d_in[5];
    const float* bk    = (const float*)d_in[6];
    const float* Wv    = (const float*)d_in[7];
    const float* bv    = (const float*)d_in[8];
    const float* Wo    = (const float*)d_in[9];
    const float* bo    = (const float*)d_in[10];
    float* out = (float*)d_out;

    // ws (u16): xb 4M | wtq|wtk|wtv 3M | wto 1M | q 4M | k 4M | VT 4M |
    //           bias3 (3072 f32, padded to 4096) | cs table (2048x32 float2)
    u16* xb  = (u16*)d_ws;
    u16* wtq = xb + (size_t)BS_ * DIM_;
    u16* wtk = wtq + (size_t)DIM_ * DIM_;
    u16* wtv = wtk + (size_t)DIM_ * DIM_;
    u16* wto = wtv + (size_t)DIM_ * DIM_;
    u16* qws = wto + (size_t)DIM_ * DIM_;
    u16* kws = qws + BHSD;
    u16* vtw = kws + BHSD;
    float* bias3 = (float*)(vtw + BHSD);
    float2* cs = (float2*)(bias3 + 4096);

    // fused prep: cvt_x | wtrans(+perm) | cos/sin table | bias concat(+perm)
    prep<<<dim3(6412), dim3(256), 0, stream>>>(
        x, xb, Wq, Wk, Wv, Wo, wtq, wtk, wtv, wto, bq, bk, bv, bias3, theta, cs);

    // fused QKV projection: q,k rope'd head-major; V transposed+pi-permuted
    gemm_mfma<128, 0, 0><<<dim3(32, 24), dim3(256), 0, stream>>>(
        xb, wtq, bias3, qws, cs);

    // all-active attention: 1024 co-resident blocks, 4 active waves/SIMD
    attn_q<<<dim3(32, 32), dim3(256), 0, stream>>>(qws, kws, vtw);

    // output projection (head-major A in, fp32 row-major out)
    gemm_mfma<64, 1, 1><<<dim3(32, 16), dim3(256), 0, stream>>>(
        qws, wto, bo, out, cs);
}

// Round 10
// 91.181 us; speedup vs baseline: 2.4464x; 1.0876x over previous
//
#include <hip/hip_runtime.h>
#include <math.h>

#define B_   2
#define S_   2048
#define DIM_ 1024
#define H_   16
#define HD_  64
#define BS_  (B_ * S_)              // 4096
#define BHSD ((size_t)B_ * H_ * S_ * HD_)   // 4M elements
#define CEXP 0.1803368801111244f    // log2(e) / sqrt(64)

typedef unsigned short u16;
typedef unsigned int   u32;
typedef short s16x8 __attribute__((ext_vector_type(8)));
typedef float f32x4 __attribute__((ext_vector_type(4)));

#define MFMA16(a, b, c) __builtin_amdgcn_mfma_f32_16x16x32_bf16((a), (b), (c), 0, 0, 0)

__device__ __forceinline__ u16 f2bf(float f) {
    u32 u = __float_as_uint(f);
    u += 0x7fffu + ((u >> 16) & 1u);            // RNE
    return (u16)(u >> 16);
}
__device__ __forceinline__ u32 cvt_pk_bf16(float a, float b) {
    u32 r;
    asm("v_cvt_pk_bf16_f32 %0, %1, %2" : "=v"(r) : "v"(a), "v"(b));
    return r;
}
// async global->LDS, 16B/lane; LDS dest must be WAVE-UNIFORM base (+lane*16)
__device__ __forceinline__ void gl16(void* lds, const void* g) {
    __builtin_amdgcn_global_load_lds(
        (__attribute__((address_space(1))) void*)(g),
        (__attribute__((address_space(3))) void*)(lds), 16, 0, 0);
}

// ---------------------------------------------------------------------------
// prep: fused cvt_x | weight transpose (+q/k col-permutation) | cos/sin table
// | bias concat (permuted). Dispatch by blockIdx.x range.
//   [0, 2048)      : x fp32 -> bf16 (8 elems/thread)
//   [2048, 6144)   : W z=idx>>10 transpose 32x32; z<2 get rope col-perm
//   [6144, 6400)   : cs table: cs[s*32+j] = (cos(s*theta[j]), sin(...))
//   [6400, 6412)   : bias3 concat with q/k permutation
// ---------------------------------------------------------------------------
__global__ __launch_bounds__(256) void prep(
    const float* __restrict__ x, u16* __restrict__ xb,
    const float* __restrict__ W0, const float* __restrict__ W1,
    const float* __restrict__ W2, const float* __restrict__ W3,
    u16* __restrict__ T0, u16* __restrict__ T1,
    u16* __restrict__ T2, u16* __restrict__ T3,
    const float* __restrict__ bq, const float* __restrict__ bk,
    const float* __restrict__ bv, float* __restrict__ bias3,
    const float* __restrict__ theta, float2* __restrict__ cs)
{
    __shared__ float tile[32][33];
    const int bid = blockIdx.x, tid = threadIdx.x;

    if (bid < 2048) {                       // ---- x -> bf16
        const int i = bid * 256 + tid;
        const float4 a = *(const float4*)(x + (size_t)i * 8);
        const float4 b = *(const float4*)(x + (size_t)i * 8 + 4);
        s16x8 o;
        o[0] = (short)f2bf(a.x); o[1] = (short)f2bf(a.y);
        o[2] = (short)f2bf(a.z); o[3] = (short)f2bf(a.w);
        o[4] = (short)f2bf(b.x); o[5] = (short)f2bf(b.y);
        o[6] = (short)f2bf(b.z); o[7] = (short)f2bf(b.w);
        *(s16x8*)(xb + (size_t)i * 8) = o;
    } else if (bid < 6144) {                // ---- W transpose
        const int idx = bid - 2048;
        const int z = idx >> 10;
        const float* W; u16* T;
        switch (z) {
            case 0: W = W0; T = T0; break;
            case 1: W = W1; T = T1; break;
            case 2: W = W2; T = T2; break;
            default: W = W3; T = T3; break;
        }
        const int n0 = ((idx >> 5) & 31) * 32, k0 = (idx & 31) * 32;
        const int c = tid & 31, rr = tid >> 5;
#pragma unroll
        for (int i = 0; i < 4; ++i) {
            const int k = rr + i * 8;
            tile[k][c] = W[(size_t)(k0 + k) * DIM_ + n0 + c];
        }
        __syncthreads();
#pragma unroll
        for (int i = 0; i < 4; ++i) {
            const int col = n0 + rr + i * 8;
            int pcol = col;
            if (z < 2) {                    // rope col-perm: even->lo, odd->hi
                const int dd = col & 63;
                const int pd = (dd & 1) ? 32 + (dd >> 1) : (dd >> 1);
                pcol = (col & ~63) | pd;
            }
            T[(size_t)pcol * DIM_ + k0 + c] = f2bf(tile[c][rr + i * 8]);
        }
    } else if (bid < 6400) {                // ---- cos/sin table
        const int idx = bid - 6144;
        const int s = idx * 8 + (tid >> 5), j = tid & 31;
        float sn, cn;
        sincosf((float)s * theta[j], &sn, &cn);
        cs[(s << 5) + j] = make_float2(cn, sn);
    } else {                                // ---- bias concat (permuted q,k)
        const int i = (bid - 6400) * 256 + tid;   // 0..3071
        const int which = i >> 10, local = i & 1023;
        const float v = (which == 0) ? bq[local]
                      : (which == 1) ? bk[local] : bv[local];
        int dst = i;
        if (which < 2) {
            const int dd = local & 63;
            const int pd = (dd & 1) ? 32 + (dd >> 1) : (dd >> 1);
            dst = which * 1024 + (local & ~63) + pd;
        }
        bias3[dst] = v;
    }
}

// ---------------------------------------------------------------------------
// bf16 MFMA GEMM, tile 128 x BN, BK=64, 256 threads (4 waves, 2x2 quadrants).
// A,Bt staged via global_load_lds (16B) into linear LDS, XOR-swizzled via
// pre-swizzled global source.
// EPI 0: bf16 head-major out into q|k|VT.
//   q,k: fused RoPE (weights col-permuted; pairs (n, n+2) in-register) +
//        q pre-scaled by log2(e)/8.
//   VT : V transposed with kv-bit perm pi: bits[5,4,3,2]->[2,5,4,3]
//        (makes the attention PV A-fragment lane-local).
// EPI 1: fp32 row-major out.
// ---------------------------------------------------------------------------
template<int BN, int HMIN, int EPI>
__global__ __launch_bounds__(256, 3) void gemm_mfma(
    const u16* __restrict__ A, const u16* __restrict__ Bt,
    const float* __restrict__ bias, void* __restrict__ Yv,
    const float2* __restrict__ cs)
{
    __shared__ u16 As[128 * 64];
    __shared__ u16 Bs[BN * 64];

    const int tid = threadIdx.x, lane = tid & 63, wid = tid >> 6;
    const int l15 = lane & 15, lg = lane >> 4;
    const int row0 = blockIdx.x * 128, col0 = blockIdx.y * BN;
    const int wr = (wid >> 1) * 64;
    const int wc = (wid & 1) * (BN / 2);
    constexpr int NM = 4, NN = BN / 32, BCH = BN / 32;

    const int l8 = lane >> 3, l7 = lane & 7;
    const int colE = ((l7 ^ l8) << 3);          // k-element offset (swizzled)

    const u16* aptr[4]; u16* aldp[4];
#pragma unroll
    for (int i = 0; i < 4; ++i) {
        const int ci = wid * 4 + i;
        const int rr = row0 + ci * 8 + l8;
        size_t a0;
        if (HMIN)
            a0 = (((size_t)(rr >> 11) * H_) * S_ + (rr & (S_ - 1))) * HD_ + colE;
        else
            a0 = (size_t)rr * DIM_ + colE;
        aptr[i] = A + a0;
        aldp[i] = As + ci * 512;
    }
    const u16* bptr[BCH]; u16* bldp[BCH];
#pragma unroll
    for (int i = 0; i < BCH; ++i) {
        const int ci = wid * BCH + i;
        const int rr = col0 + ci * 8 + l8;
        bptr[i] = Bt + (size_t)rr * DIM_ + colE;
        bldp[i] = Bs + ci * 512;
    }
    const size_t astep = HMIN ? (size_t)S_ * HD_ : 64;

    f32x4 acc[NM][NN];
#pragma unroll
    for (int m = 0; m < NM; ++m)
#pragma unroll
        for (int n = 0; n < NN; ++n) acc[m][n] = (f32x4){0.f, 0.f, 0.f, 0.f};

    for (int k0 = 0; k0 < DIM_; k0 += 64) {
        __syncthreads();   // previous frag reads done
#pragma unroll
        for (int i = 0; i < 4; ++i) gl16(aldp[i], aptr[i]);
#pragma unroll
        for (int i = 0; i < BCH; ++i) gl16(bldp[i], bptr[i]);
#pragma unroll
        for (int i = 0; i < 4; ++i) aptr[i] += astep;
#pragma unroll
        for (int i = 0; i < BCH; ++i) bptr[i] += 64;
        __syncthreads();   // loads drained

        s16x8 af[NM][2], bfr[NN][2];
#pragma unroll
        for (int m = 0; m < NM; ++m) {
            const int row = wr + m * 16 + l15;
#pragma unroll
            for (int kf = 0; kf < 2; ++kf)
                af[m][kf] = *(const s16x8*)&As[row * 64 +
                    (((kf * 64 + lg * 16) ^ ((l15 & 7) << 4)) >> 1)];
        }
#pragma unroll
        for (int n = 0; n < NN; ++n) {
            const int row = wc + n * 16 + l15;
#pragma unroll
            for (int kf = 0; kf < 2; ++kf)
                bfr[n][kf] = *(const s16x8*)&Bs[row * 64 +
                    (((kf * 64 + lg * 16) ^ ((l15 & 7) << 4)) >> 1)];
        }
        __builtin_amdgcn_s_setprio(1);
#pragma unroll
        for (int m = 0; m < NM; ++m)
#pragma unroll
            for (int n = 0; n < NN; ++n) {
                acc[m][n] = MFMA16(af[m][0], bfr[n][0], acc[m][n]);
                acc[m][n] = MFMA16(af[m][1], bfr[n][1], acc[m][n]);
            }
        __builtin_amdgcn_s_setprio(0);
    }

    // ---- epilogue
    if (EPI == 0) {
        u16* Y = (u16*)Yv;
        const int whichq = (col0 + wc) >> 10;          // wave-uniform
        if (whichq < 2) {
            // fused RoPE: pairs (n, n+2); out d = j and j+32
            const float sclw = (whichq == 0) ? CEXP : 1.0f;
#pragma unroll
            for (int n = 0; n < 2; ++n) {
                const int cc0 = col0 + wc + n * 16 + l15;
                const int j = n * 16 + l15;            // 0..31
                const float bv0 = bias[cc0];
                const float bv1 = bias[cc0 + 32];
                const int hh = (cc0 >> 6) & (H_ - 1);
#pragma unroll
                for (int m = 0; m < NM; ++m)
#pragma unroll
                    for (int r = 0; r < 4; ++r) {
                        const int rr = row0 + wr + m * 16 + lg * 4 + r;
                        const int b = rr >> 11, s = rr & (S_ - 1);
                        const float2 csv = cs[(s << 5) + j];
                        const float v0 = acc[m][n][r] + bv0;
                        const float v1 = acc[m][n + 2][r] + bv1;
                        const size_t base = (size_t)whichq * BHSD
                            + (((size_t)b * H_ + hh) * S_ + s) * HD_;
                        Y[base + j]      = f2bf((v0 * csv.x - v1 * csv.y) * sclw);
                        Y[base + j + 32] = f2bf((v0 * csv.y + v1 * csv.x) * sclw);
                    }
            }
        } else {
#pragma unroll
            for (int n = 0; n < NN; ++n) {
                const int cc = col0 + wc + n * 16 + l15;
                const float bv = bias[cc];
                const int hh = (cc >> 6) & (H_ - 1), d = cc & 63;
#pragma unroll
                for (int m = 0; m < NM; ++m)
#pragma unroll
                    for (int r = 0; r < 4; ++r) {
                        const int rr = row0 + wr + m * 16 + lg * 4 + r;
                        const int b = rr >> 11, s = rr & (S_ - 1);
                        // V^T with kv perm pi: bits {2,3}->{3,4}, {4}->{5}, {5}->{2}
                        const int sp = (s & ~60) | ((s & 12) << 1)
                                     | ((s & 16) << 1) | ((s & 32) >> 3);
                        Y[2 * BHSD + ((size_t)(b * H_ + hh) * HD_ + d) * S_ + sp] =
                            f2bf(acc[m][n][r] + bv);
                    }
            }
        }
    } else {
#pragma unroll
        for (int n = 0; n < NN; ++n) {
            const int cc = col0 + wc + n * 16 + l15;
            const float bv = bias[cc];
#pragma unroll
            for (int m = 0; m < NM; ++m)
#pragma unroll
                for (int r = 0; r < 4; ++r) {
                    const int rr = row0 + wr + m * 16 + lg * 4 + r;
                    ((float*)Yv)[(size_t)rr * DIM_ + cc] = acc[m][n][r] + bv;
                }
        }
    }
}

// ---------------------------------------------------------------------------
// Causal flash attention, max-free: p = exp2(score) directly (scores are
// log2-scaled via Q pre-scale; common factor cancels in O/l), row-sum l
// computed on the MATRIX pipe via a ones-column B-fragment in the same
// accumulator layout as O -> epilogue divides with zero shuffles.
// One 64-row q-tile per 256-thread block (4 waves x 16 q-rows, all active).
// Grid (32 bh FAST, 32 qt DESC) = 1024 co-resident blocks. KV staged
// 64 rows/step, double-buffered via global_load_lds with XOR swizzle.
// Swapped QK^T MFMA16; pi-permuted V^T -> lane-local PV A-fragments.
// Output in place into Q.
// ---------------------------------------------------------------------------
__global__ __launch_bounds__(256, 4) void attn_q(
    u16* __restrict__ Q, const u16* __restrict__ K, const u16* __restrict__ VT)
{
    const int bh = blockIdx.x;
    const int qt = 31 - blockIdx.y;           // heavy blocks dispatch first
    const int nsteps = qt + 1;

    u16* Qg = Q + (size_t)bh * S_ * HD_;
    const u16* Kg = K + (size_t)bh * S_ * HD_;
    const u16* Vg = VT + (size_t)bh * HD_ * S_;   // pi-permuted [64][2048]

    __shared__ u16 Ks[2][64 * 64];   // 2 x 8 KB
    __shared__ u16 Vs[2][64 * 64];   // 2 x 8 KB

    const int tid = threadIdx.x;
    const int w = tid >> 6, lane = tid & 63;
    const int q0 = qt * 64 + w * 16;
    const int l15 = lane & 15, lg = lane >> 4;

    // staging: per wave 2 K-chunks + 2 V-chunks (8 rows x 64 cols each)
    const int crow = lane >> 3, cslt = lane & 7;

    auto stage = [&](int bufi, int j0) {
#pragma unroll
        for (int i = 0; i < 2; ++i) {
            const int c = w * 2 + i;                  // chunk 0..7
            const int row = c * 8 + crow;             // 0..63
            const int soff = ((cslt ^ (row & 7)) << 3);
            gl16(&Ks[bufi][c * 512], Kg + (size_t)(j0 + row) * HD_ + soff);
            gl16(&Vs[bufi][c * 512], Vg + (size_t)row * S_ + j0 + soff);
        }
    };

    // Q fragments: rows q0 + l15 (rope'd, q pre-scaled by log2(e)/8)
    s16x8 qf[2];
    {
        const u16* qrow = Qg + (size_t)(q0 + l15) * HD_ + lg * 8;
        qf[0] = *(const s16x8*)(qrow);
        qf[1] = *(const s16x8*)(qrow + 32);
    }

    // ones B-fragment (bf16 1.0 in every slot) for MFMA row-sums
    s16x8 onesv;
#pragma unroll
    for (int i = 0; i < 8; ++i) onesv[i] = (short)0x3F80;

    f32x4 o[4], ol;
#pragma unroll
    for (int n = 0; n < 4; ++n) o[n] = (f32x4){0.f, 0.f, 0.f, 0.f};
    ol = (f32x4){0.f, 0.f, 0.f, 0.f};

    stage(0, 0);
    __syncthreads();

    int buf = 0;
    for (int t = 0; t < nsteps; ++t) {
        if (t + 1 < nsteps) stage(buf ^ 1, (t + 1) * 64);   // prefetch

        const u16* Kb = Ks[buf];
        const u16* Vb = Vs[buf];

        // ---- swapped QK^T: sc[sub][r] = S[kv=t*64+sub*16+lg*4+r][q0+l15]
        f32x4 sc[4];
        __builtin_amdgcn_s_setprio(1);
#pragma unroll
        for (int sub = 0; sub < 4; ++sub) {
            const int kr = sub * 16 + l15;
            const s16x8 kf0 = *(const s16x8*)&Kb[kr * 64 + ((lg ^ (kr & 7)) << 3)];
            const s16x8 kf1 = *(const s16x8*)&Kb[kr * 64 + (((lg + 4) ^ (kr & 7)) << 3)];
            f32x4 z = (f32x4){0.f, 0.f, 0.f, 0.f};
            z = MFMA16(kf0, qf[0], z);
            sc[sub] = MFMA16(kf1, qf[1], z);
        }
        __builtin_amdgcn_s_setprio(0);

        if (t == qt) {      // diagonal 64-tile: aligned 16x16 subs
#pragma unroll
            for (int sub = 0; sub < 4; ++sub) {
                if (sub == w) {
#pragma unroll
                    for (int r = 0; r < 4; ++r)
                        if (lg * 4 + r > l15) sc[sub][r] = -1e30f;
                } else if (sub > w) {
#pragma unroll
                    for (int r = 0; r < 4; ++r) sc[sub][r] = -1e30f;
                }
            }
        }

        // ---- max-free softmax: p = exp2(s); masked -1e30 -> exp2 -> 0
        float p[4][4];
#pragma unroll
        for (int sub = 0; sub < 4; ++sub)
#pragma unroll
            for (int r = 0; r < 4; ++r)
                p[sub][r] = __builtin_amdgcn_exp2f(sc[sub][r]);

        // ---- PV + row-sum: lane-local A-fragments (pi-permuted V^T)
        union { s16x8 v; u32 w4[4]; } af[2];
#pragma unroll
        for (int step = 0; step < 2; ++step)
#pragma unroll
            for (int jj = 0; jj < 4; ++jj) {
                const int sub = (jj >> 1) * 2 + step;
                const int r0  = (jj & 1) * 2;
                af[step].w4[jj] = cvt_pk_bf16(p[sub][r0], p[sub][r0 + 1]);
            }
        __builtin_amdgcn_s_setprio(1);
#pragma unroll
        for (int n = 0; n < 4; ++n) {
            const int d = n * 16 + l15;
            const s16x8 vf0 = *(const s16x8*)&Vb[d * 64 + ((lg ^ (d & 7)) << 3)];
            const s16x8 vf1 = *(const s16x8*)&Vb[d * 64 + (((lg + 4) ^ (d & 7)) << 3)];
            o[n] = MFMA16(af[0].v, vf0, o[n]);
            o[n] = MFMA16(af[1].v, vf1, o[n]);
        }
        ol = MFMA16(af[0].v, onesv, ol);    // l[q] = sum_kv p (matrix pipe)
        ol = MFMA16(af[1].v, onesv, ol);
        __builtin_amdgcn_s_setprio(0);

        __syncthreads();   // drains prefetch; buffer handoff
        buf ^= 1;
    }

    // ---- epilogue: O / l (register-local, no shuffles), in place into Q
    f32x4 il;
#pragma unroll
    for (int r = 0; r < 4; ++r) il[r] = 1.f / ol[r];
    u16* orow = Qg + (size_t)(q0 + lg * 4) * HD_ + l15;
#pragma unroll
    for (int r = 0; r < 4; ++r)
#pragma unroll
        for (int n = 0; n < 4; ++n)
            orow[r * HD_ + n * 16] = f2bf(o[n][r] * il[r]);
}

// ---------------------------------------------------------------------------
extern "C" void kernel_launch(void* const* d_in, const int* in_sizes, int n_in,
                              void* d_out, int out_size, void* d_ws, size_t ws_size,
                              hipStream_t stream)
{
    (void)in_sizes; (void)n_in; (void)out_size; (void)ws_size;
    const float* x     = (const float*)d_in[0];
    const float* theta = (const float*)d_in[2];
    const float* Wq    = (const float*)d_in[3];
    const float* bq    = (const float*)d_in[4];
    const float* Wk    = (const float*)d_in[5];
    const float* bk    = (const float*)d_in[6];
    const float* Wv    = (const float*)d_in[7];
    const float* bv    = (const float*)d_in[8];
    const float* Wo    = (const float*)d_in[9];
    const float* bo    = (const float*)d_in[10];
    float* out = (float*)d_out;

    // ws (u16): xb 4M | wtq|wtk|wtv 3M | wto 1M | q 4M | k 4M | VT 4M |
    //           bias3 (3072 f32, padded to 4096) | cs table (2048x32 float2)
    u16* xb  = (u16*)d_ws;
    u16* wtq = xb + (size_t)BS_ * DIM_;
    u16* wtk = wtq + (size_t)DIM_ * DIM_;
    u16* wtv = wtk + (size_t)DIM_ * DIM_;
    u16* wto = wtv + (size_t)DIM_ * DIM_;
    u16* qws = wto + (size_t)DIM_ * DIM_;
    u16* kws = qws + BHSD;
    u16* vtw = kws + BHSD;
    float* bias3 = (float*)(vtw + BHSD);
    float2* cs = (float2*)(bias3 + 4096);

    // fused prep: cvt_x | wtrans(+perm) | cos/sin table | bias concat(+perm)
    prep<<<dim3(6412), dim3(256), 0, stream>>>(
        x, xb, Wq, Wk, Wv, Wo, wtq, wtk, wtv, wto, bq, bk, bv, bias3, theta, cs);

    // fused QKV projection: q,k rope'd head-major; V transposed+pi-permuted
    gemm_mfma<128, 0, 0><<<dim3(32, 24), dim3(256), 0, stream>>>(
        xb, wtq, bias3, qws, cs);

    // max-free attention: 1024 co-resident blocks, matrix-pipe row sums
    attn_q<<<dim3(32, 32), dim3(256), 0, stream>>>(qws, kws, vtw);

    // output projection (head-major A in, fp32 row-major out)
    gemm_mfma<64, 1, 1><<<dim3(32, 16), dim3(256), 0, stream>>>(
        qws, wto, bo, out, cs);
}